// Round 1
// baseline (1589.914 us; speedup 1.0000x reference)
//
#include <hip/hip_runtime.h>
#include <hip/hip_bf16.h>

// Problem constants
#define BB 16
#define SS 1024
#define DD 1024

typedef __hip_bfloat16 bf;
using s8v   = __attribute__((ext_vector_type(8))) short;
using f32x4 = __attribute__((ext_vector_type(4))) float;
using u16x4 = __attribute__((ext_vector_type(4))) unsigned short;

// Async global->LDS, 16 B per lane. LDS dest = wave-uniform base + lane*16.
__device__ __forceinline__ void gload16(const bf* g, unsigned short* l)
{
    __builtin_amdgcn_global_load_lds(
        (const __attribute__((address_space(1))) void*)g,
        (__attribute__((address_space(3))) void*)l,
        16, 0, 0);
}

// ---------------------------------------------------------------------------
// bf16 NT GEMM with MFMA 16x16x32. 128x128 tile, 4 waves (2x2), 64x64/wave.
// Staging via global_load_lds width=16 (m97 structure).
//   C[m,n] (+)= alpha * sum_k A[m,k]*B[n,k]  (+ bias[n]) (+ addc)
// EP=0: fp32 out (optional accumulate). EP=1: bf16 out.
// EP=2: QK 4-plane split-write. v = acc + bias. col<1024 -> Q: v*=Wf0
//   (alpha), planes [hi|hi|lo] at row stride 4096; col>=1024 -> K:
//   planes [hi|lo|hi] at row stride 4096. (Plane 3 = ctx, filled later.)
// M,N multiples of 128, K multiple of 32.
// ---------------------------------------------------------------------------
template <int EP>
__global__ __launch_bounds__(256) void gemm_bf16_nt(
    const bf* __restrict__ A, long sA, int lda,
    const bf* __restrict__ B, long sB, int ldb,
    float* __restrict__ C, bf* __restrict__ Cb,
    bf* __restrict__ qp, bf* __restrict__ kp,
    long sC, int ldc, int K,
    const float* __restrict__ bias,
    const float* __restrict__ alpha_ptr, int alpha_idx,
    const float* __restrict__ addc_ptr,
    int accumulate)
{
    // Unpadded row-major tiles: 128 rows x 32 bf16 (64 B/row) = 8 KB each.
    __shared__ __align__(16) unsigned short As[128 * 32];
    __shared__ __align__(16) unsigned short Bs[128 * 32];

    const int tid  = threadIdx.x;
    const int wave = tid >> 6, lane = tid & 63;
    const int wm = (wave >> 1) * 64, wn = (wave & 1) * 64;
    const int lm = lane & 15, quad = lane >> 4;

    const int m0 = blockIdx.y * 128, n0 = blockIdx.x * 128;
    const bf* Ab = A + (long)blockIdx.z * sA;
    const bf* Bb = B + (long)blockIdx.z * sB;

    // Staging map: wave w covers tile rows [w*32, w*32+32), two 1-KB issues
    // (16 rows each). Lane i -> row = base + i/4, col = (i%4)*8 (16 B).
    const int srow = wave * 32 + (lane >> 2);   // issue-0 row for this lane
    const int scol = (lane & 3) * 8;            // bf16 column offset
    unsigned short* lA0 = &As[(wave * 32) * 32];
    unsigned short* lA1 = &As[(wave * 32 + 16) * 32];
    unsigned short* lB0 = &Bs[(wave * 32) * 32];
    unsigned short* lB1 = &Bs[(wave * 32 + 16) * 32];

    f32x4 acc[4][4];
#pragma unroll
    for (int i = 0; i < 4; ++i)
#pragma unroll
        for (int j = 0; j < 4; ++j)
            acc[i][j] = (f32x4){0.f, 0.f, 0.f, 0.f};

    const bf* gA0 = Ab + (long)(m0 + srow) * lda + scol;
    const bf* gA1 = Ab + (long)(m0 + srow + 16) * lda + scol;
    const bf* gB0 = Bb + (long)(n0 + srow) * ldb + scol;
    const bf* gB1 = Bb + (long)(n0 + srow + 16) * ldb + scol;

    for (int k0 = 0; k0 < K; k0 += 32) {
        __syncthreads();                 // prior iter's ds_reads complete
        gload16(gA0 + k0, lA0);
        gload16(gA1 + k0, lA1);
        gload16(gB0 + k0, lB0);
        gload16(gB1 + k0, lB1);
        __syncthreads();                 // drains vmcnt -> LDS visible

        s8v a[4], b[4];
#pragma unroll
        for (int i = 0; i < 4; ++i) a[i] = *(const s8v*)&As[(wm + 16 * i + lm) * 32 + quad * 8];
#pragma unroll
        for (int j = 0; j < 4; ++j) b[j] = *(const s8v*)&Bs[(wn + 16 * j + lm) * 32 + quad * 8];
#pragma unroll
        for (int i = 0; i < 4; ++i)
#pragma unroll
            for (int j = 0; j < 4; ++j)
                acc[i][j] = __builtin_amdgcn_mfma_f32_16x16x32_bf16(a[i], b[j], acc[i][j], 0, 0, 0);
    }

    const float alpha = alpha_ptr ? alpha_ptr[alpha_idx] : 1.0f;
    const float addc  = addc_ptr ? addc_ptr[0] : 0.0f;
    float* Cp = C ? C + (long)blockIdx.z * sC : nullptr;
    bf* Cbp = (EP == 1) ? Cb + (long)blockIdx.z * sC : nullptr;

#pragma unroll
    for (int i = 0; i < 4; ++i) {
#pragma unroll
        for (int j = 0; j < 4; ++j) {
            const int cidx = n0 + wn + 16 * j + lm;
            const float bv = bias ? bias[cidx] : 0.0f;
            const long rbase = m0 + wm + 16 * i + quad * 4;
#pragma unroll
            for (int r = 0; r < 4; ++r) {
                const long row = rbase + r;
                if (EP == 2) {
                    float v = acc[i][j][r] + bv;
                    if (cidx < 1024) {
                        v *= alpha;      // fold Wf[0] into Q planes (exact: split after scale)
                        bf hi = __float2bfloat16(v);
                        bf lo = __float2bfloat16(v - __bfloat162float(hi));
                        qp[row * 4096 + cidx] = hi;
                        qp[row * 4096 + 1024 + cidx] = hi;
                        qp[row * 4096 + 2048 + cidx] = lo;
                    } else {
                        const int c = cidx - 1024;
                        bf hi = __float2bfloat16(v);
                        bf lo = __float2bfloat16(v - __bfloat162float(hi));
                        kp[row * 4096 + c] = hi;
                        kp[row * 4096 + 1024 + c] = lo;
                        kp[row * 4096 + 2048 + c] = hi;
                    }
                } else {
                    float v = alpha * acc[i][j][r] + addc + bv;
                    const long off = row * (long)ldc + cidx;
                    if (EP == 1) {
                        Cbp[off] = __float2bfloat16(v);
                    } else {
                        if (accumulate) v += Cp[off];
                        Cp[off] = v;
                    }
                }
            }
        }
    }
}

// ---------------------------------------------------------------------------
// Block reductions (256 threads = 4 waves of 64)
// ---------------------------------------------------------------------------
__device__ inline float blockReduceSum(float v, float* red)
{
#pragma unroll
    for (int off = 32; off > 0; off >>= 1) v += __shfl_xor(v, off, 64);
    __syncthreads();
    if ((threadIdx.x & 63) == 0) red[threadIdx.x >> 6] = v;
    __syncthreads();
    return red[0] + red[1] + red[2] + red[3];
}

__device__ inline float blockReduceMax(float v, float* red)
{
#pragma unroll
    for (int off = 32; off > 0; off >>= 1) v = fmaxf(v, __shfl_xor(v, off, 64));
    __syncthreads();
    if ((threadIdx.x & 63) == 0) red[threadIdx.x >> 6] = v;
    __syncthreads();
    return fmaxf(fmaxf(red[0], red[1]), fmaxf(red[2], red[3]));
}

__device__ inline void split_bf16(float v, bf& hi, bf& lo)
{
    hi = __float2bfloat16(v);
    lo = __float2bfloat16(v - __bfloat162float(hi));
}

// ---------------------------------------------------------------------------
// Weight prep (once per launch)
// ---------------------------------------------------------------------------
// Wqkv (2048x1024 fp32) -> Wq3 (2048x3072: [Whi|Whi|Wlo]) matching
// A = [xhi|xlo|xhi]: seg0 xhi*Whi + seg1 xlo*Whi + seg2 xhi*Wlo.
__global__ __launch_bounds__(256) void prep_wqkv_kernel(
    const float* __restrict__ W, bf* __restrict__ wq3)
{
    long i = (long)blockIdx.x * 256 + threadIdx.x;   // 2048*1024 threads
    long r = i >> 10; int c = (int)(i & 1023);
    bf hi, lo; split_bf16(W[i], hi, lo);
    wq3[r * 3072 + c] = hi;
    wq3[r * 3072 + 1024 + c] = hi;
    wq3[r * 3072 + 2048 + c] = lo;
}

// plain fp32 -> bf16 with source stride
__global__ __launch_bounds__(256) void conv_kernel(
    const float* __restrict__ src, bf* __restrict__ dst, int cols, int src_ld, long n)
{
    long i = (long)blockIdx.x * 256 + threadIdx.x;
    if (i >= n) return;
    long r = i / cols; int c = (int)(i % cols);
    dst[i] = __float2bfloat16(src[r * src_ld + c]);
}

// ---------------------------------------------------------------------------
// x -> xh3 (S x 3072: [hi|lo|hi]) and xT1 (D x S, bf16 hi). grid (32,32,G).
// Plane 1 (lo) is consumed only by the qkv GEMM; step 8 later reuses it
// to hold valb so [hi|valb] is contiguous for the fused output GEMM.
// ---------------------------------------------------------------------------
__global__ __launch_bounds__(256) void conv_x_kernel(
    const float* __restrict__ x, bf* __restrict__ xh3, bf* __restrict__ xT1)
{
    __shared__ float t[32][33];
    const int b = blockIdx.z;
    const int c0 = blockIdx.x * 32, r0 = blockIdx.y * 32;
    const int tx = threadIdx.x & 31, ty = threadIdx.x >> 5;  // ty 0..7
    const float* xb = x + (long)b * SS * DD;
    bf* xb3 = xh3 + (long)b * SS * 3072;
#pragma unroll
    for (int p = 0; p < 4; ++p) {
        const int r = ty + 8 * p;
        const float v = xb[(long)(r0 + r) * DD + c0 + tx];
        t[r][tx] = v;
        bf hi, lo; split_bf16(v, hi, lo);
        xb3[(long)(r0 + r) * 3072 + c0 + tx] = hi;
        xb3[(long)(r0 + r) * 3072 + 1024 + c0 + tx] = lo;
        xb3[(long)(r0 + r) * 3072 + 2048 + c0 + tx] = hi;
    }
    __syncthreads();
#pragma unroll
    for (int p = 0; p < 4; ++p) {
        const int rr = ty + 8 * p;
        xT1[(long)b * DD * SS + (long)(c0 + rr) * SS + r0 + tx] =
            __float2bfloat16(t[tx][rr]);
    }
}

// ---------------------------------------------------------------------------
// L2-normalize each half-row (1024) of ctx bf16 (rows of 2048); write the
// normalized vector into plane 3 of Q4 (q-half, scaled by Wf[1]) or K4
// (k-half). grid = nrows*2, block 256.
// ---------------------------------------------------------------------------
__global__ __launch_bounds__(256) void l2norm_fuse_kernel(
    const bf* __restrict__ ctx, bf* __restrict__ q4, bf* __restrict__ k4,
    const float* __restrict__ Wf)
{
    __shared__ float red[4];
    const long row = blockIdx.x >> 1;
    const int half = blockIdx.x & 1;
    const bf* p = ctx + row * 2048 + half * 1024;
    const int t = threadIdx.x;

    const u16x4 u = *reinterpret_cast<const u16x4*>(p + 4 * t);
    float v[4];
    float ss = 0.0f;
#pragma unroll
    for (int i = 0; i < 4; ++i) {
        unsigned short us = u[i];
        v[i] = __bfloat162float(*reinterpret_cast<const bf*>(&us));
        ss = fmaf(v[i], v[i], ss);
    }
    ss = blockReduceSum(ss, red);
    const float inv = 1.0f / fmaxf(sqrtf(ss), 1e-12f);
    const float scale = half ? inv : inv * Wf[1];   // fold Wf[1] into ctx_q
    bf* dst = (half ? k4 : q4) + row * 4096 + 3072 + 4 * t;
    u16x4 o;
#pragma unroll
    for (int i = 0; i < 4; ++i) {
        bf h = __float2bfloat16(v[i] * scale);
        o[i] = *reinterpret_cast<unsigned short*>(&h);
    }
    *reinterpret_cast<u16x4*>(dst) = o;
}

// ---------------------------------------------------------------------------
// softmax -> mask -> L1 renorm, row 1024, fp32 in -> bf16 out. grid = nrows.
// ---------------------------------------------------------------------------
__global__ __launch_bounds__(256) void softmax_mask_kernel(
    const float* __restrict__ attn, const int* __restrict__ mask, bf* __restrict__ attn_bf)
{
    __shared__ float red[4];
    const long row = blockIdx.x;
    const float* p = attn + row * SS;
    const int* mrow = mask + row * SS;
    bf* o = attn_bf + row * SS;
    const int t = threadIdx.x;

    float v[4];
    int mv[4];
#pragma unroll
    for (int i = 0; i < 4; ++i) { v[i] = p[t + 256 * i]; mv[i] = mrow[t + 256 * i]; }
    float mx = fmaxf(fmaxf(v[0], v[1]), fmaxf(v[2], v[3]));
    mx = blockReduceMax(mx, red);

    float e[4];
    float s = 0.0f;
#pragma unroll
    for (int i = 0; i < 4; ++i) { e[i] = expf(v[i] - mx); s += e[i]; }
    s = blockReduceSum(s, red);

    float l1 = 0.0f;
#pragma unroll
    for (int i = 0; i < 4; ++i) { e[i] = mv[i] ? e[i] / s : 0.0f; l1 += e[i]; }
    l1 = blockReduceSum(l1, red);
    const float inv = 1.0f / fmaxf(l1, 1e-12f);
#pragma unroll
    for (int i = 0; i < 4; ++i) o[t + 256 * i] = __float2bfloat16(e[i] * inv);
}

// ---------------------------------------------------------------------------
extern "C" void kernel_launch(void* const* d_in, const int* in_sizes, int n_in,
                              void* d_out, int out_size, void* d_ws, size_t ws_size,
                              hipStream_t stream)
{
    const float* x    = (const float*)d_in[0];
    const int*   mask = (const int*)d_in[1];
    const float* Wqkv = (const float*)d_in[2];
    const float* bqkv = (const float*)d_in[3];
    const float* Wctx = (const float*)d_in[4];
    const float* bctx = (const float*)d_in[5];
    const float* Wf   = (const float*)d_in[6];
    const float* bfp  = (const float*)d_in[7];
    const float* Wo   = (const float*)d_in[8];
    const float* bo   = (const float*)d_in[9];
    float* out = (float*)d_out;

    const long SD = (long)SS * DD;                 // 1M elements per batch

    auto align_up = [](size_t v) { return (v + 255) & ~(size_t)255; };

    // Shared weight buffers
    const size_t sz_wq3  = 2048L * 3072 * 2;       // 12.6 MB [Whi|Whi|Wlo]
    const size_t sz_wctx = 2048L * 1024 * 2;       // 4.19 MB
    const size_t sz_wob  = 1024L * 2048 * 2;       // 4.19 MB full Wo
    const size_t SH = align_up(sz_wq3) + align_up(sz_wctx) + align_up(sz_wob);

    // Per-batch pooled regions:
    //   RX (6.29 MB): xh3 [hi|lo|hi]; plane 1 becomes valb after step 8
    //   RT (2.10 MB): xT1
    //   RQ (8.39 MB): Q4 [Qhi|Qhi|Qlo|cq]; attnb aliases head after step 6
    //   RK (8.39 MB): K4 [Khi|Klo|Khi|ck]
    //   RY (4.19 MB): Y1 -> attn fp32 (Y1 dead after step 4)
    //   RC (4.19 MB): ctx bf16 (pre-norm)
    const size_t szX3 = 1024L * 3072 * 2;
    const size_t szXT = 1024L * 1024 * 2;
    const size_t szQ4 = 1024L * 4096 * 2;
    const size_t szY  = 2048L * 1024 * 2;          // == 1024*1024*4 (attn fp32)
    const size_t szC  = 1024L * 2048 * 2;
    const size_t PB = align_up(szX3) + align_up(szXT) + 2 * align_up(szQ4) +
                      align_up(szY) + align_up(szC);

    int G = 16;
    while (G > 1 && SH + (size_t)G * PB > ws_size) G >>= 1;

    char* p = (char*)d_ws;
    auto take = [&](size_t bytes) { char* r = p; p += align_up(bytes); return r; };
    bf* Wq3   = (bf*)take(sz_wq3);
    bf* Wctx1 = (bf*)take(sz_wctx);
    bf* Wob   = (bf*)take(sz_wob);
    char* RX = take((size_t)G * szX3);
    char* RT = take((size_t)G * szXT);
    char* RQ = take((size_t)G * szQ4);
    char* RK = take((size_t)G * szQ4);
    char* RY = take((size_t)G * szY);
    char* RC = take((size_t)G * szC);

    bf*    xh3   = (bf*)RX;                        // G x (1024 x 3072)
    bf*    xT1   = (bf*)RT;                        // G x (1024 x 1024)
    bf*    Q4    = (bf*)RQ;                        // G x (1024 x 4096)
    bf*    K4    = (bf*)RK;                        // G x (1024 x 4096)
    bf*    Y1    = (bf*)RY;                        // G x (2048 x 1024)
    float* attn  = (float*)RY;                     // G x (1024 x 1024) fp32
    bf*    ctxb  = (bf*)RC;                        // G x (1024 x 2048)
    bf*    attnb = (bf*)RQ;                        // G x (1024 x 1024)

    const dim3 blk(256);
    const long sX3 = 1024L * 3072;
    const long sAT = 1024L * 1024;
    const long sQ4 = 1024L * 4096;
    const long sY  = 2048L * 1024;
    const long sCt = 1024L * 2048;

    // --- weight prep (once) ---
    prep_wqkv_kernel<<<dim3((2048L * 1024) / 256), blk, 0, stream>>>(Wqkv, Wq3);
    conv_kernel<<<dim3((2048L * 1024) / 256), blk, 0, stream>>>(Wctx, Wctx1, 1024, 1024, 2048L * 1024);
    conv_kernel<<<dim3((1024L * 2048) / 256), blk, 0, stream>>>(Wo, Wob, 2048, 2048, 1024L * 2048);

    for (int bc0 = 0; bc0 < BB; bc0 += G) {
        const float* xb = x + (long)bc0 * SD;
        const int M = G * 1024;                    // flattened rows this chunk

        // 0. x -> xh3 ([hi|lo|hi]), xT1
        conv_x_kernel<<<dim3(32, 32, G), blk, 0, stream>>>(xb, xh3, xT1);

        // 1. qkv = [xhi|xlo|xhi] * [Whi|Whi|Wlo]^T + bqkv  (K=3072, flat M)
        //    epilogue: Q planes (x Wf0) -> Q4[0..3071], K planes -> K4[0..3071]
        gemm_bf16_nt<2><<<dim3(16, M / 128), blk, 0, stream>>>(
            xh3, 0, 3072, Wq3, 0, 3072,
            nullptr, nullptr, Q4, K4, 0, 0, 3072,
            bqkv, Wf, 0, nullptr, 0);

        // 2. Y1 = Wctx * x^T  (NT via xT1), bf16 out (per batch)
        gemm_bf16_nt<1><<<dim3(8, 16, G), blk, 0, stream>>>(
            Wctx1, 0, 1024, xT1, sAT, 1024,
            nullptr, Y1, nullptr, nullptr, sY, 1024, 1024,
            nullptr, nullptr, 0, nullptr, 0);

        // 3. ctxb = bf16(xhi * Y1^T + bctx)                (per batch)
        gemm_bf16_nt<1><<<dim3(16, 8, G), blk, 0, stream>>>(
            xh3, sX3, 3072, Y1, sY, 1024,
            nullptr, ctxb, nullptr, nullptr, sCt, 2048, 1024,
            bctx, nullptr, 0, nullptr, 0);

        // 4. L2-normalize halves -> Q4/K4 plane 3 (q scaled by Wf1)
        l2norm_fuse_kernel<<<dim3(G * 1024 * 2), blk, 0, stream>>>(ctxb, Q4, K4, Wf);

        // 5. attn = Q4 * K4^T + bf   (K=4096: Wf0*(qhi*khi+qhi*klo+qlo*khi)
        //    + Wf1*(cq*ck), one pass, single fp32 write)
        gemm_bf16_nt<0><<<dim3(8, 8, G), blk, 0, stream>>>(
            Q4, sQ4, 4096, K4, sQ4, 4096,
            attn, nullptr, nullptr, nullptr, sAT, 1024, 4096,
            nullptr, nullptr, 0, bfp, 0);

        // 6. softmax -> mask -> L1 renorm -> attnb
        softmax_mask_kernel<<<dim3(G * 1024), blk, 0, stream>>>(
            attn, mask + (long)bc0 * SS * SS, attnb);

        // 7. valb = attnb * x^T (NT via xT1), bf16 into xh3 plane 1
        gemm_bf16_nt<1><<<dim3(8, 8, G), blk, 0, stream>>>(
            attnb, sAT, 1024, xT1, sAT, 1024,
            nullptr, xh3 + 1024, nullptr, nullptr, sX3, 3072, 1024,
            nullptr, nullptr, 0, nullptr, 0);

        // 8. out = [xhi|valb] * Wo^T + bo   (K=2048, flat M, single write)
        gemm_bf16_nt<0><<<dim3(8, M / 128), blk, 0, stream>>>(
            xh3, 0, 3072, Wob, 0, 2048,
            out + (long)bc0 * SD, nullptr, nullptr, nullptr, 0, 1024, 2048,
            bo, nullptr, 0, nullptr, 0);
    }
}

// Round 2
// 1333.750 us; speedup vs baseline: 1.1921x; 1.1921x over previous
//
#include <hip/hip_runtime.h>
#include <hip/hip_bf16.h>

// Problem constants
#define BB 16
#define SS 1024
#define DD 1024

typedef __hip_bfloat16 bf;
using s8v   = __attribute__((ext_vector_type(8))) short;
using f32x4 = __attribute__((ext_vector_type(4))) float;
using u16x4 = __attribute__((ext_vector_type(4))) unsigned short;

// Async global->LDS, 16 B per lane. LDS dest = wave-uniform base + lane*16.
__device__ __forceinline__ void gload16(const bf* g, unsigned short* l)
{
    __builtin_amdgcn_global_load_lds(
        (const __attribute__((address_space(1))) void*)g,
        (__attribute__((address_space(3))) void*)l,
        16, 0, 0);
}

// ---------------------------------------------------------------------------
// bf16 NT GEMM with MFMA 16x16x32. 128x128 tile, 4 waves (2x2), 64x64/wave.
// Staging via global_load_lds width=16 (m97 structure).
//   C[m,n] (+)= alpha * sum_k A[m,k]*B[n,k]  (+ bias[n]) (+ addc)
// kwrapA: effective A column = (k0 >= kwrapA ? k0 - kwrapA : k0). Lets the
//   K=3072 qkv GEMM reuse the xhi plane of a 2-plane [hi|lo] A buffer for
//   its third K-segment (pass kwrapA = K for normal GEMMs).
// EP=0: fp32 out (optional accumulate). EP=1: bf16 out.
// EP=2: QK plane split-write (flat rows). v = acc + bias. col<1024 -> Q:
//   v*=Wf0 (alpha), planes [hi|hi|lo] at row stride 4096; col>=1024 -> K:
//   planes [hi|lo|hi] at row stride 4096. (Plane 3 = ctx, filled later.)
// EP=3: ctx split-write (per-batch rows, z-stride sC on qp/kp): bf16(v)
//   into plane 3: col<1024 -> qp[row*4096+3072+col], else kp[...+col-1024].
// M,N multiples of 128, K multiple of 32.
// ---------------------------------------------------------------------------
template <int EP>
__global__ __launch_bounds__(256) void gemm_bf16_nt(
    const bf* __restrict__ A, long sA, int lda, int kwrapA,
    const bf* __restrict__ B, long sB, int ldb,
    float* __restrict__ C, bf* __restrict__ Cb,
    bf* __restrict__ qp, bf* __restrict__ kp,
    long sC, int ldc, int K,
    const float* __restrict__ bias,
    const float* __restrict__ alpha_ptr, int alpha_idx,
    const float* __restrict__ addc_ptr,
    int accumulate)
{
    // Unpadded row-major tiles: 128 rows x 32 bf16 (64 B/row) = 8 KB each.
    __shared__ __align__(16) unsigned short As[128 * 32];
    __shared__ __align__(16) unsigned short Bs[128 * 32];

    const int tid  = threadIdx.x;
    const int wave = tid >> 6, lane = tid & 63;
    const int wm = (wave >> 1) * 64, wn = (wave & 1) * 64;
    const int lm = lane & 15, quad = lane >> 4;

    const int m0 = blockIdx.y * 128, n0 = blockIdx.x * 128;
    const bf* Ab = A + (long)blockIdx.z * sA;
    const bf* Bb = B + (long)blockIdx.z * sB;

    // Staging map: wave w covers tile rows [w*32, w*32+32), two 1-KB issues
    // (16 rows each). Lane i -> row = base + i/4, col = (i%4)*8 (16 B).
    const int srow = wave * 32 + (lane >> 2);   // issue-0 row for this lane
    const int scol = (lane & 3) * 8;            // bf16 column offset
    unsigned short* lA0 = &As[(wave * 32) * 32];
    unsigned short* lA1 = &As[(wave * 32 + 16) * 32];
    unsigned short* lB0 = &Bs[(wave * 32) * 32];
    unsigned short* lB1 = &Bs[(wave * 32 + 16) * 32];

    f32x4 acc[4][4];
#pragma unroll
    for (int i = 0; i < 4; ++i)
#pragma unroll
        for (int j = 0; j < 4; ++j)
            acc[i][j] = (f32x4){0.f, 0.f, 0.f, 0.f};

    const bf* gA0 = Ab + (long)(m0 + srow) * lda + scol;
    const bf* gA1 = Ab + (long)(m0 + srow + 16) * lda + scol;
    const bf* gB0 = Bb + (long)(n0 + srow) * ldb + scol;
    const bf* gB1 = Bb + (long)(n0 + srow + 16) * ldb + scol;

    for (int k0 = 0; k0 < K; k0 += 32) {
        const int ka = (k0 >= kwrapA) ? k0 - kwrapA : k0;   // A-plane wrap
        __syncthreads();                 // prior iter's ds_reads complete
        gload16(gA0 + ka, lA0);
        gload16(gA1 + ka, lA1);
        gload16(gB0 + k0, lB0);
        gload16(gB1 + k0, lB1);
        __syncthreads();                 // drains vmcnt -> LDS visible

        s8v a[4], b[4];
#pragma unroll
        for (int i = 0; i < 4; ++i) a[i] = *(const s8v*)&As[(wm + 16 * i + lm) * 32 + quad * 8];
#pragma unroll
        for (int j = 0; j < 4; ++j) b[j] = *(const s8v*)&Bs[(wn + 16 * j + lm) * 32 + quad * 8];
#pragma unroll
        for (int i = 0; i < 4; ++i)
#pragma unroll
            for (int j = 0; j < 4; ++j)
                acc[i][j] = __builtin_amdgcn_mfma_f32_16x16x32_bf16(a[i], b[j], acc[i][j], 0, 0, 0);
    }

    const float alpha = alpha_ptr ? alpha_ptr[alpha_idx] : 1.0f;
    const float addc  = addc_ptr ? addc_ptr[0] : 0.0f;
    float* Cp = C ? C + (long)blockIdx.z * sC : nullptr;
    bf* Cbp = (EP == 1) ? Cb + (long)blockIdx.z * sC : nullptr;
    bf* qpz = (EP == 2 || EP == 3) ? qp + (long)blockIdx.z * sC : nullptr;
    bf* kpz = (EP == 2 || EP == 3) ? kp + (long)blockIdx.z * sC : nullptr;

#pragma unroll
    for (int i = 0; i < 4; ++i) {
#pragma unroll
        for (int j = 0; j < 4; ++j) {
            const int cidx = n0 + wn + 16 * j + lm;
            const float bv = bias ? bias[cidx] : 0.0f;
            const long rbase = m0 + wm + 16 * i + quad * 4;
#pragma unroll
            for (int r = 0; r < 4; ++r) {
                const long row = rbase + r;
                if (EP == 2) {
                    float v = acc[i][j][r] + bv;
                    if (cidx < 1024) {
                        v *= alpha;      // fold Wf[0] into Q planes (exact: split after scale)
                        bf hi = __float2bfloat16(v);
                        bf lo = __float2bfloat16(v - __bfloat162float(hi));
                        qpz[row * 4096 + cidx] = hi;
                        qpz[row * 4096 + 1024 + cidx] = hi;
                        qpz[row * 4096 + 2048 + cidx] = lo;
                    } else {
                        const int c = cidx - 1024;
                        bf hi = __float2bfloat16(v);
                        bf lo = __float2bfloat16(v - __bfloat162float(hi));
                        kpz[row * 4096 + c] = hi;
                        kpz[row * 4096 + 1024 + c] = lo;
                        kpz[row * 4096 + 2048 + c] = hi;
                    }
                } else if (EP == 3) {
                    const float v = acc[i][j][r] + bv;
                    const bf h = __float2bfloat16(v);
                    if (cidx < 1024) qpz[row * 4096 + 3072 + cidx] = h;
                    else             kpz[row * 4096 + 3072 + (cidx - 1024)] = h;
                } else {
                    float v = alpha * acc[i][j][r] + addc + bv;
                    const long off = row * (long)ldc + cidx;
                    if (EP == 1) {
                        Cbp[off] = __float2bfloat16(v);
                    } else {
                        if (accumulate) v += Cp[off];
                        Cp[off] = v;
                    }
                }
            }
        }
    }
}

// ---------------------------------------------------------------------------
// Block reductions (256 threads = 4 waves of 64)
// ---------------------------------------------------------------------------
__device__ inline float blockReduceSum(float v, float* red)
{
#pragma unroll
    for (int off = 32; off > 0; off >>= 1) v += __shfl_xor(v, off, 64);
    __syncthreads();
    if ((threadIdx.x & 63) == 0) red[threadIdx.x >> 6] = v;
    __syncthreads();
    return red[0] + red[1] + red[2] + red[3];
}

__device__ inline float blockReduceMax(float v, float* red)
{
#pragma unroll
    for (int off = 32; off > 0; off >>= 1) v = fmaxf(v, __shfl_xor(v, off, 64));
    __syncthreads();
    if ((threadIdx.x & 63) == 0) red[threadIdx.x >> 6] = v;
    __syncthreads();
    return fmaxf(fmaxf(red[0], red[1]), fmaxf(red[2], red[3]));
}

__device__ inline void split_bf16(float v, bf& hi, bf& lo)
{
    hi = __float2bfloat16(v);
    lo = __float2bfloat16(v - __bfloat162float(hi));
}

// ---------------------------------------------------------------------------
// Weight prep (once per launch)
// ---------------------------------------------------------------------------
// Wqkv (2048x1024 fp32) -> Wq3 (2048x3072: [Whi|Whi|Wlo]) matching the
// wrapped A = [xhi|xlo|(xhi)]: seg0 xhi*Whi + seg1 xlo*Whi + seg2 xhi*Wlo.
__global__ __launch_bounds__(256) void prep_wqkv_kernel(
    const float* __restrict__ W, bf* __restrict__ wq3)
{
    long i = (long)blockIdx.x * 256 + threadIdx.x;   // 2048*1024 threads
    long r = i >> 10; int c = (int)(i & 1023);
    bf hi, lo; split_bf16(W[i], hi, lo);
    wq3[r * 3072 + c] = hi;
    wq3[r * 3072 + 1024 + c] = hi;
    wq3[r * 3072 + 2048 + c] = lo;
}

// plain fp32 -> bf16 with source stride
__global__ __launch_bounds__(256) void conv_kernel(
    const float* __restrict__ src, bf* __restrict__ dst, int cols, int src_ld, long n)
{
    long i = (long)blockIdx.x * 256 + threadIdx.x;
    if (i >= n) return;
    long r = i / cols; int c = (int)(i % cols);
    dst[i] = __float2bfloat16(src[r * src_ld + c]);
}

// ---------------------------------------------------------------------------
// x -> xhl (S x 2048: [hi|lo]) and xT1 (D x S, bf16 hi). grid (32,32,G).
// The lo plane is consumed only by the qkv GEMM; step 7 later reuses it
// to hold valb so [hi|valb] is contiguous for the fused output GEMM.
// ---------------------------------------------------------------------------
__global__ __launch_bounds__(256) void conv_x_kernel(
    const float* __restrict__ x, bf* __restrict__ xhl, bf* __restrict__ xT1)
{
    __shared__ float t[32][33];
    const int b = blockIdx.z;
    const int c0 = blockIdx.x * 32, r0 = blockIdx.y * 32;
    const int tx = threadIdx.x & 31, ty = threadIdx.x >> 5;  // ty 0..7
    const float* xb = x + (long)b * SS * DD;
    bf* xhlb = xhl + (long)b * SS * 2048;
#pragma unroll
    for (int p = 0; p < 4; ++p) {
        const int r = ty + 8 * p;
        const float v = xb[(long)(r0 + r) * DD + c0 + tx];
        t[r][tx] = v;
        bf hi, lo; split_bf16(v, hi, lo);
        xhlb[(long)(r0 + r) * 2048 + c0 + tx] = hi;
        xhlb[(long)(r0 + r) * 2048 + 1024 + c0 + tx] = lo;
    }
    __syncthreads();
#pragma unroll
    for (int p = 0; p < 4; ++p) {
        const int rr = ty + 8 * p;
        xT1[(long)b * DD * SS + (long)(c0 + rr) * SS + r0 + tx] =
            __float2bfloat16(t[tx][rr]);
    }
}

// ---------------------------------------------------------------------------
// In-place L2-normalize plane 3 of Q4 (even blocks, scaled by Wf[1]) / K4
// (odd blocks). Rows are at row*4096 + 3072 globally (per-batch stride
// 1024*4096 folds into row*4096). grid = nrows*2, block 256.
// ---------------------------------------------------------------------------
__global__ __launch_bounds__(256) void l2norm_fuse_kernel(
    bf* __restrict__ q4, bf* __restrict__ k4, const float* __restrict__ Wf)
{
    __shared__ float red[4];
    const long row = blockIdx.x >> 1;
    const int half = blockIdx.x & 1;
    bf* p = (half ? k4 : q4) + row * 4096 + 3072;
    const int t = threadIdx.x;

    const u16x4 u = *reinterpret_cast<const u16x4*>(p + 4 * t);
    float v[4];
    float ss = 0.0f;
#pragma unroll
    for (int i = 0; i < 4; ++i) {
        unsigned short us = u[i];
        v[i] = __bfloat162float(*reinterpret_cast<const bf*>(&us));
        ss = fmaf(v[i], v[i], ss);
    }
    ss = blockReduceSum(ss, red);
    const float inv = 1.0f / fmaxf(sqrtf(ss), 1e-12f);
    const float scale = half ? inv : inv * Wf[1];   // fold Wf[1] into ctx_q
    u16x4 o;
#pragma unroll
    for (int i = 0; i < 4; ++i) {
        bf h = __float2bfloat16(v[i] * scale);
        o[i] = *reinterpret_cast<unsigned short*>(&h);
    }
    *reinterpret_cast<u16x4*>(p + 4 * t) = o;
}

// ---------------------------------------------------------------------------
// softmax -> mask -> L1 renorm, row 1024, fp32 in -> bf16 out. grid = nrows.
// ---------------------------------------------------------------------------
__global__ __launch_bounds__(256) void softmax_mask_kernel(
    const float* __restrict__ attn, const int* __restrict__ mask, bf* __restrict__ attn_bf)
{
    __shared__ float red[4];
    const long row = blockIdx.x;
    const float* p = attn + row * SS;
    const int* mrow = mask + row * SS;
    bf* o = attn_bf + row * SS;
    const int t = threadIdx.x;

    float v[4];
    int mv[4];
#pragma unroll
    for (int i = 0; i < 4; ++i) { v[i] = p[t + 256 * i]; mv[i] = mrow[t + 256 * i]; }
    float mx = fmaxf(fmaxf(v[0], v[1]), fmaxf(v[2], v[3]));
    mx = blockReduceMax(mx, red);

    float e[4];
    float s = 0.0f;
#pragma unroll
    for (int i = 0; i < 4; ++i) { e[i] = expf(v[i] - mx); s += e[i]; }
    s = blockReduceSum(s, red);

    float l1 = 0.0f;
#pragma unroll
    for (int i = 0; i < 4; ++i) { e[i] = mv[i] ? e[i] / s : 0.0f; l1 += e[i]; }
    l1 = blockReduceSum(l1, red);
    const float inv = 1.0f / fmaxf(l1, 1e-12f);
#pragma unroll
    for (int i = 0; i < 4; ++i) o[t + 256 * i] = __float2bfloat16(e[i] * inv);
}

// ---------------------------------------------------------------------------
extern "C" void kernel_launch(void* const* d_in, const int* in_sizes, int n_in,
                              void* d_out, int out_size, void* d_ws, size_t ws_size,
                              hipStream_t stream)
{
    const float* x    = (const float*)d_in[0];
    const int*   mask = (const int*)d_in[1];
    const float* Wqkv = (const float*)d_in[2];
    const float* bqkv = (const float*)d_in[3];
    const float* Wctx = (const float*)d_in[4];
    const float* bctx = (const float*)d_in[5];
    const float* Wf   = (const float*)d_in[6];
    const float* bfp  = (const float*)d_in[7];
    const float* Wo   = (const float*)d_in[8];
    const float* bo   = (const float*)d_in[9];
    float* out = (float*)d_out;

    const long SD = (long)SS * DD;                 // 1M elements per batch

    auto align_up = [](size_t v) { return (v + 255) & ~(size_t)255; };

    // Shared weight buffers
    const size_t sz_wq3  = 2048L * 3072 * 2;       // 12.6 MB [Whi|Whi|Wlo]
    const size_t sz_wctx = 2048L * 1024 * 2;       // 4.19 MB
    const size_t sz_wob  = 1024L * 2048 * 2;       // 4.19 MB full Wo
    const size_t SH = align_up(sz_wq3) + align_up(sz_wctx) + align_up(sz_wob);

    // Per-batch pooled regions (total 27262976 B == round-0 footprint):
    //   RX (4.19 MB): xhl [hi|lo]; lo plane becomes valb after step 7
    //   RT (2.10 MB): xT1
    //   RQ (8.39 MB): Q4 [Qhi|Qhi|Qlo|cq]; attnb aliases head after step 5
    //   RK (8.39 MB): K4 [Khi|Klo|Khi|ck]
    //   RY (4.19 MB): Y1 -> attn fp32 (Y1 dead after step 3)
    const size_t szXL = 1024L * 2048 * 2;
    const size_t szXT = 1024L * 1024 * 2;
    const size_t szQ4 = 1024L * 4096 * 2;
    const size_t szY  = 2048L * 1024 * 2;          // == 1024*1024*4 (attn fp32)
    const size_t PB = align_up(szXL) + align_up(szXT) + 2 * align_up(szQ4) +
                      align_up(szY);

    int G = 16;
    while (G > 1 && SH + (size_t)G * PB > ws_size) G >>= 1;

    char* p = (char*)d_ws;
    auto take = [&](size_t bytes) { char* r = p; p += align_up(bytes); return r; };
    bf* Wq3   = (bf*)take(sz_wq3);
    bf* Wctx1 = (bf*)take(sz_wctx);
    bf* Wob   = (bf*)take(sz_wob);
    char* RX = take((size_t)G * szXL);
    char* RT = take((size_t)G * szXT);
    char* RQ = take((size_t)G * szQ4);
    char* RK = take((size_t)G * szQ4);
    char* RY = take((size_t)G * szY);

    bf*    xhl   = (bf*)RX;                        // G x (1024 x 2048)
    bf*    xT1   = (bf*)RT;                        // G x (1024 x 1024)
    bf*    Q4    = (bf*)RQ;                        // G x (1024 x 4096)
    bf*    K4    = (bf*)RK;                        // G x (1024 x 4096)
    bf*    Y1    = (bf*)RY;                        // G x (2048 x 1024)
    float* attn  = (float*)RY;                     // G x (1024 x 1024) fp32
    bf*    attnb = (bf*)RQ;                        // G x (1024 x 1024)

    const dim3 blk(256);
    const long sXL = 1024L * 2048;
    const long sAT = 1024L * 1024;
    const long sQ4 = 1024L * 4096;
    const long sY  = 2048L * 1024;

    // --- weight prep (once) ---
    prep_wqkv_kernel<<<dim3((2048L * 1024) / 256), blk, 0, stream>>>(Wqkv, Wq3);
    conv_kernel<<<dim3((2048L * 1024) / 256), blk, 0, stream>>>(Wctx, Wctx1, 1024, 1024, 2048L * 1024);
    conv_kernel<<<dim3((1024L * 2048) / 256), blk, 0, stream>>>(Wo, Wob, 2048, 2048, 1024L * 2048);

    for (int bc0 = 0; bc0 < BB; bc0 += G) {
        const float* xb = x + (long)bc0 * SD;
        const int M = G * 1024;                    // flattened rows this chunk

        // 0. x -> xhl ([hi|lo]), xT1
        conv_x_kernel<<<dim3(32, 32, G), blk, 0, stream>>>(xb, xhl, xT1);

        // 1. qkv = [xhi|xlo|(xhi)] * [Whi|Whi|Wlo]^T + bqkv  (K=3072, flat M,
        //    A wraps at 2048). Epilogue: Q planes (x Wf0) -> Q4, K -> K4.
        gemm_bf16_nt<2><<<dim3(16, M / 128), blk, 0, stream>>>(
            xhl, 0, 2048, 2048, Wq3, 0, 3072,
            nullptr, nullptr, Q4, K4, 0, 0, 3072,
            bqkv, Wf, 0, nullptr, 0);

        // 2. Y1 = Wctx * x^T  (NT via xT1), bf16 out (per batch)
        gemm_bf16_nt<1><<<dim3(8, 16, G), blk, 0, stream>>>(
            Wctx1, 0, 1024, 1024, xT1, sAT, 1024,
            nullptr, Y1, nullptr, nullptr, sY, 1024, 1024,
            nullptr, nullptr, 0, nullptr, 0);

        // 3. ctx = xhi * Y1^T + bctx -> bf16 straight into Q4/K4 plane 3
        gemm_bf16_nt<3><<<dim3(16, 8, G), blk, 0, stream>>>(
            xhl, sXL, 2048, 1024, Y1, sY, 1024,
            nullptr, nullptr, Q4, K4, sQ4, 0, 1024,
            bctx, nullptr, 0, nullptr, 0);

        // 4. L2-normalize plane 3 in place (q half scaled by Wf1)
        l2norm_fuse_kernel<<<dim3(G * 1024 * 2), blk, 0, stream>>>(Q4, K4, Wf);

        // 5. attn = Q4 * K4^T + bf   (K=4096: Wf0*(qhi*khi+qhi*klo+qlo*khi)
        //    + Wf1*(cq*ck), one pass, single fp32 write)
        gemm_bf16_nt<0><<<dim3(8, 8, G), blk, 0, stream>>>(
            Q4, sQ4, 4096, 4096, K4, sQ4, 4096,
            attn, nullptr, nullptr, nullptr, sAT, 1024, 4096,
            nullptr, nullptr, 0, bfp, 0);

        // 6. softmax -> mask -> L1 renorm -> attnb
        softmax_mask_kernel<<<dim3(G * 1024), blk, 0, stream>>>(
            attn, mask + (long)bc0 * SS * SS, attnb);

        // 7. valb = attnb * x^T (NT via xT1), bf16 into xhl lo plane
        gemm_bf16_nt<1><<<dim3(8, 8, G), blk, 0, stream>>>(
            attnb, sAT, 1024, 1024, xT1, sAT, 1024,
            nullptr, xhl + 1024, nullptr, nullptr, sXL, 2048, 1024,
            nullptr, nullptr, 0, nullptr, 0);

        // 8. out = [xhi|valb] * Wo^T + bo   (K=2048, flat M, single write)
        gemm_bf16_nt<0><<<dim3(8, M / 128), blk, 0, stream>>>(
            xhl, 0, 2048, 2048, Wob, 0, 2048,
            out + (long)bc0 * SD, nullptr, nullptr, nullptr, 0, 1024, 2048,
            bo, nullptr, 0, nullptr, 0);
    }
}

// Round 3
// 1150.292 us; speedup vs baseline: 1.3822x; 1.1595x over previous
//
#include <hip/hip_runtime.h>
#include <hip/hip_bf16.h>

// Problem constants
#define BB 16
#define SS 1024
#define DD 1024

typedef __hip_bfloat16 bf;
using s8v   = __attribute__((ext_vector_type(8))) short;
using f32x4 = __attribute__((ext_vector_type(4))) float;
using u16x4 = __attribute__((ext_vector_type(4))) unsigned short;

// Async global->LDS, 16 B per lane. LDS dest = wave-uniform base + lane*16.
__device__ __forceinline__ void gload16(const bf* g, unsigned short* l)
{
    __builtin_amdgcn_global_load_lds(
        (const __attribute__((address_space(1))) void*)g,
        (__attribute__((address_space(3))) void*)l,
        16, 0, 0);
}

// Raw barrier (NO implicit vmcnt drain, unlike __syncthreads) + sched fences.
__device__ __forceinline__ void phase_barrier()
{
    __builtin_amdgcn_sched_barrier(0);
    __builtin_amdgcn_s_barrier();
    __builtin_amdgcn_sched_barrier(0);
}

// ---------------------------------------------------------------------------
// 256x256 8-phase bf16 NT GEMM (MFMA 16x16x32), BK=64, 8 waves (2Mx4N),
// 512 threads, 128 KiB LDS double-buffered, XOR-swizzled LDS via pre-swizzled
// global source (global_load_lds writes linearly). Counted vmcnt(6) pipeline:
// per tile t: ph1 stages B(t+1)h1, ph3 stages A(t+2)h0+h1, ph4 stages
// B(t+2)h0 + vmcnt(6). Each same-buffer stage is issued in the phase AFTER
// that LDS region's last read -> no write/read latency races.
//   C[m,n] (+)= alpha * sum_k A[m,k]*B[n,k]  (+ bias[n]) (+ addc)
// kwrapA: effective A column = (k0 >= kwrapA ? k0 - kwrapA : k0)  (qkv wrap).
// EP=0: fp32 out (optional accumulate). EP=1: bf16 out.
// EP=2: QK plane split-write (flat rows, sC=0). v = acc + bias. col<1024 ->
//   Q: v*=Wf0(alpha), planes [hi|hi|lo] row-stride 4096; col>=1024 -> K:
//   planes [hi|lo|hi]. (Plane 3 = ctx, filled later.)
// EP=3: ctx split-write into plane 3 of qp/kp (z-stride sC).
// M,N multiples of 256, K multiple of 64 (K/64 >= 4).
// ---------------------------------------------------------------------------
template <int EP>
__global__ __launch_bounds__(512, 2) void gemm256(
    const bf* __restrict__ A, long sA, int lda, int kwrapA,
    const bf* __restrict__ B, long sB, int ldb,
    float* __restrict__ C, bf* __restrict__ Cb,
    bf* __restrict__ qp, bf* __restrict__ kp,
    long sC, int ldc, int K,
    const float* __restrict__ bias,
    const float* __restrict__ alpha_ptr, int alpha_idx,
    const float* __restrict__ addc_ptr,
    int accumulate)
{
    // A: [2 dbuf][2 half][128 rows][64 cols] bf16 = 64 KB, then B same.
    __shared__ __align__(16) unsigned short lds[65536];
    unsigned short* Asm = lds;            // 4 * 8192 shorts
    unsigned short* Bsm = lds + 32768;

    const int tid = threadIdx.x;
    const int w = tid >> 6, l = tid & 63;
    const int wm = w >> 2, wn = w & 3;    // 2 x 4 wave grid
    const int lm = l & 15, quad = l >> 4;
    const int bh = wn >> 1;               // B half this wave reads
    const int bl0 = (wn & 1) * 64;        // B local row base within half

    const int m0 = blockIdx.y * 256, n0 = blockIdx.x * 256;
    const bf* Ab = A + (long)blockIdx.z * sA;
    const bf* Bb = B + (long)blockIdx.z * sB;

    // Staging source map (pre-swizzled so linear LDS + swizzled read agree):
    // issue q of wave w -> half-local row = w*16 + q*8 + (l>>3),
    // 16B-chunk index = (l&7) ^ (l>>3)  -> element col = chunk*8.
    const int srow = w * 16 + (l >> 3);
    const int scol = ((l & 7) ^ (l >> 3)) << 3;
    const long aoff0 = (long)srow * lda + scol;
    const long aoff1 = (long)(srow + 8) * lda + scol;
    const long boff0 = (long)srow * ldb + scol;
    const long boff1 = (long)(srow + 8) * ldb + scol;
    const int ldst = w * 1024;            // shorts; +512 for issue q=1

    auto stageA = [&](int tt, int h) {
        int kk = tt << 6;
        if (kk >= kwrapA) kk -= kwrapA;
        const bf* g = Ab + (long)(m0 + h * 128) * lda + kk;
        unsigned short* d = Asm + (((tt & 1) << 1) + h) * 8192 + ldst;
        gload16(g + aoff0, d);
        gload16(g + aoff1, d + 512);
    };
    auto stageB = [&](int tt, int h) {
        const int kk = tt << 6;
        const bf* g = Bb + (long)(n0 + h * 128) * ldb + kk;
        unsigned short* d = Bsm + (((tt & 1) << 1) + h) * 8192 + ldst;
        gload16(g + boff0, d);
        gload16(g + boff1, d + 512);
    };
    // Swizzled LDS fragment reads (rl&7 == lm&7 since frag rows are 16-aligned)
    auto rdA = [&](int d, int rl, int ks) -> s8v {
        const int off = rl * 64 + (((ks << 5) + (quad << 3)) ^ ((rl & 7) << 3));
        return *(const s8v*)(Asm + ((d << 1) + wm) * 8192 + off);
    };
    auto rdB = [&](int d, int bl, int ks) -> s8v {
        const int off = bl * 64 + (((ks << 5) + (quad << 3)) ^ ((bl & 7) << 3));
        return *(const s8v*)(Bsm + ((d << 1) + bh) * 8192 + off);
    };

    f32x4 acc[8][4];
#pragma unroll
    for (int i = 0; i < 8; ++i)
#pragma unroll
        for (int j = 0; j < 4; ++j)
            acc[i][j] = (f32x4){0.f, 0.f, 0.f, 0.f};

    const int NT = K >> 6;

    // Prologue: tile0 (4 HT), vmcnt(4); tile1 A-halves + Bh0 (3 HT); vmcnt(6).
    stageA(0, 0); stageA(0, 1); stageB(0, 0); stageB(0, 1);
    __builtin_amdgcn_sched_barrier(0);
    asm volatile("s_waitcnt vmcnt(4)" ::: "memory");
    __builtin_amdgcn_sched_barrier(0);
    stageA(1, 0); stageA(1, 1); stageB(1, 0);
    __builtin_amdgcn_sched_barrier(0);
    asm volatile("s_waitcnt vmcnt(6)" ::: "memory");
    __builtin_amdgcn_sched_barrier(0);
    phase_barrier();

    s8v a[8], b[4];
    for (int t = 0; t < NT; ++t) {
        const int d = t & 1;
        // ---- phase 1: Q1 = M0 x N0 (12 ds_reads; stage B(t+1)h1) ----
#pragma unroll
        for (int mf = 0; mf < 4; ++mf) {
            a[mf * 2]     = rdA(d, mf * 16 + lm, 0);
            a[mf * 2 + 1] = rdA(d, mf * 16 + lm, 1);
        }
#pragma unroll
        for (int nf = 0; nf < 2; ++nf) {
            b[nf * 2]     = rdB(d, bl0 + nf * 16 + lm, 0);
            b[nf * 2 + 1] = rdB(d, bl0 + nf * 16 + lm, 1);
        }
        if (t + 1 < NT) stageB(t + 1, 1);     // other dbuf: safe
        phase_barrier();
        __builtin_amdgcn_s_setprio(1);
#pragma unroll
        for (int mf = 0; mf < 4; ++mf)
#pragma unroll
            for (int nf = 0; nf < 2; ++nf) {
                acc[mf][nf] = __builtin_amdgcn_mfma_f32_16x16x32_bf16(a[mf*2],   b[nf*2],   acc[mf][nf], 0, 0, 0);
                acc[mf][nf] = __builtin_amdgcn_mfma_f32_16x16x32_bf16(a[mf*2+1], b[nf*2+1], acc[mf][nf], 0, 0, 0);
            }
        __builtin_amdgcn_s_setprio(0);
        phase_barrier();
        // ---- phase 2: Q2 = M0 x N1 (4 ds_reads; no stage) ----
#pragma unroll
        for (int nf = 0; nf < 2; ++nf) {
            b[nf * 2]     = rdB(d, bl0 + (nf + 2) * 16 + lm, 0);
            b[nf * 2 + 1] = rdB(d, bl0 + (nf + 2) * 16 + lm, 1);
        }
        phase_barrier();
        __builtin_amdgcn_s_setprio(1);
#pragma unroll
        for (int mf = 0; mf < 4; ++mf)
#pragma unroll
            for (int nf = 0; nf < 2; ++nf) {
                acc[mf][nf+2] = __builtin_amdgcn_mfma_f32_16x16x32_bf16(a[mf*2],   b[nf*2],   acc[mf][nf+2], 0, 0, 0);
                acc[mf][nf+2] = __builtin_amdgcn_mfma_f32_16x16x32_bf16(a[mf*2+1], b[nf*2+1], acc[mf][nf+2], 0, 0, 0);
            }
        __builtin_amdgcn_s_setprio(0);
        phase_barrier();
        // ---- phase 3: Q3 = M1 x N1 (8 ds_reads; stage A(t+2) both halves,
        //      issued AFTER the last A-reads of this buffer) ----
#pragma unroll
        for (int mf = 0; mf < 4; ++mf) {
            a[mf * 2]     = rdA(d, 64 + mf * 16 + lm, 0);
            a[mf * 2 + 1] = rdA(d, 64 + mf * 16 + lm, 1);
        }
        if (t + 2 < NT) { stageA(t + 2, 0); stageA(t + 2, 1); }
        phase_barrier();
        __builtin_amdgcn_s_setprio(1);
#pragma unroll
        for (int mf = 0; mf < 4; ++mf)
#pragma unroll
            for (int nf = 0; nf < 2; ++nf) {
                acc[mf+4][nf+2] = __builtin_amdgcn_mfma_f32_16x16x32_bf16(a[mf*2],   b[nf*2],   acc[mf+4][nf+2], 0, 0, 0);
                acc[mf+4][nf+2] = __builtin_amdgcn_mfma_f32_16x16x32_bf16(a[mf*2+1], b[nf*2+1], acc[mf+4][nf+2], 0, 0, 0);
            }
        __builtin_amdgcn_s_setprio(0);
        phase_barrier();
        // ---- phase 4: Q4 = M1 x N0 (4 ds_reads; stage B(t+2)h0 after the
        //      B(N0) re-read; counted vmcnt) ----
#pragma unroll
        for (int nf = 0; nf < 2; ++nf) {
            b[nf * 2]     = rdB(d, bl0 + nf * 16 + lm, 0);
            b[nf * 2 + 1] = rdB(d, bl0 + nf * 16 + lm, 1);
        }
        if (t + 2 < NT) {
            stageB(t + 2, 0);
            __builtin_amdgcn_sched_barrier(0);
            asm volatile("s_waitcnt vmcnt(6)" ::: "memory");
            __builtin_amdgcn_sched_barrier(0);
        } else {
            __builtin_amdgcn_sched_barrier(0);
            asm volatile("s_waitcnt vmcnt(0)" ::: "memory");
            __builtin_amdgcn_sched_barrier(0);
        }
        phase_barrier();
        __builtin_amdgcn_s_setprio(1);
#pragma unroll
        for (int mf = 0; mf < 4; ++mf)
#pragma unroll
            for (int nf = 0; nf < 2; ++nf) {
                acc[mf+4][nf] = __builtin_amdgcn_mfma_f32_16x16x32_bf16(a[mf*2],   b[nf*2],   acc[mf+4][nf], 0, 0, 0);
                acc[mf+4][nf] = __builtin_amdgcn_mfma_f32_16x16x32_bf16(a[mf*2+1], b[nf*2+1], acc[mf+4][nf], 0, 0, 0);
            }
        __builtin_amdgcn_s_setprio(0);
        phase_barrier();
    }

    // ------------------------------- epilogue -------------------------------
    const float alpha = alpha_ptr ? alpha_ptr[alpha_idx] : 1.0f;
    const float addc  = addc_ptr ? addc_ptr[0] : 0.0f;
    float* Cp = C ? C + (long)blockIdx.z * sC : nullptr;
    bf* Cbp = (EP == 1) ? Cb + (long)blockIdx.z * sC : nullptr;
    bf* qpz = (EP == 2 || EP == 3) ? qp + (long)blockIdx.z * sC : nullptr;
    bf* kpz = (EP == 2 || EP == 3) ? kp + (long)blockIdx.z * sC : nullptr;

#pragma unroll
    for (int mf = 0; mf < 8; ++mf) {
#pragma unroll
        for (int nf = 0; nf < 4; ++nf) {
            const int cidx = n0 + wn * 64 + nf * 16 + lm;
            const float bv = bias ? bias[cidx] : 0.0f;
            const long rbase = m0 + wm * 128 + mf * 16 + quad * 4;
#pragma unroll
            for (int r = 0; r < 4; ++r) {
                const long row = rbase + r;
                if (EP == 2) {
                    float v = acc[mf][nf][r] + bv;
                    if (cidx < 1024) {
                        v *= alpha;      // fold Wf[0] into Q planes
                        bf hi = __float2bfloat16(v);
                        bf lo = __float2bfloat16(v - __bfloat162float(hi));
                        qpz[row * 4096 + cidx] = hi;
                        qpz[row * 4096 + 1024 + cidx] = hi;
                        qpz[row * 4096 + 2048 + cidx] = lo;
                    } else {
                        const int c = cidx - 1024;
                        bf hi = __float2bfloat16(v);
                        bf lo = __float2bfloat16(v - __bfloat162float(hi));
                        kpz[row * 4096 + c] = hi;
                        kpz[row * 4096 + 1024 + c] = lo;
                        kpz[row * 4096 + 2048 + c] = hi;
                    }
                } else if (EP == 3) {
                    const float v = acc[mf][nf][r] + bv;
                    const bf h = __float2bfloat16(v);
                    if (cidx < 1024) qpz[row * 4096 + 3072 + cidx] = h;
                    else             kpz[row * 4096 + 3072 + (cidx - 1024)] = h;
                } else {
                    float v = alpha * acc[mf][nf][r] + addc + bv;
                    const long off = row * (long)ldc + cidx;
                    if (EP == 1) {
                        Cbp[off] = __float2bfloat16(v);
                    } else {
                        if (accumulate) v += Cp[off];
                        Cp[off] = v;
                    }
                }
            }
        }
    }
}

// ---------------------------------------------------------------------------
// Block reductions (256 threads = 4 waves of 64)
// ---------------------------------------------------------------------------
__device__ inline float blockReduceSum(float v, float* red)
{
#pragma unroll
    for (int off = 32; off > 0; off >>= 1) v += __shfl_xor(v, off, 64);
    __syncthreads();
    if ((threadIdx.x & 63) == 0) red[threadIdx.x >> 6] = v;
    __syncthreads();
    return red[0] + red[1] + red[2] + red[3];
}

__device__ inline float blockReduceMax(float v, float* red)
{
#pragma unroll
    for (int off = 32; off > 0; off >>= 1) v = fmaxf(v, __shfl_xor(v, off, 64));
    __syncthreads();
    if ((threadIdx.x & 63) == 0) red[threadIdx.x >> 6] = v;
    __syncthreads();
    return fmaxf(fmaxf(red[0], red[1]), fmaxf(red[2], red[3]));
}

__device__ inline void split_bf16(float v, bf& hi, bf& lo)
{
    hi = __float2bfloat16(v);
    lo = __float2bfloat16(v - __bfloat162float(hi));
}

// ---------------------------------------------------------------------------
// Weight prep (once per launch)
// ---------------------------------------------------------------------------
// Wqkv (2048x1024 fp32) -> Wq3 (2048x3072: [Whi|Whi|Wlo]) matching the
// wrapped A = [xhi|xlo|(xhi)]: seg0 xhi*Whi + seg1 xlo*Whi + seg2 xhi*Wlo.
__global__ __launch_bounds__(256) void prep_wqkv_kernel(
    const float* __restrict__ W, bf* __restrict__ wq3)
{
    long i = (long)blockIdx.x * 256 + threadIdx.x;   // 2048*1024 threads
    long r = i >> 10; int c = (int)(i & 1023);
    bf hi, lo; split_bf16(W[i], hi, lo);
    wq3[r * 3072 + c] = hi;
    wq3[r * 3072 + 1024 + c] = hi;
    wq3[r * 3072 + 2048 + c] = lo;
}

// plain fp32 -> bf16 with source stride
__global__ __launch_bounds__(256) void conv_kernel(
    const float* __restrict__ src, bf* __restrict__ dst, int cols, int src_ld, long n)
{
    long i = (long)blockIdx.x * 256 + threadIdx.x;
    if (i >= n) return;
    long r = i / cols; int c = (int)(i % cols);
    dst[i] = __float2bfloat16(src[r * src_ld + c]);
}

// ---------------------------------------------------------------------------
// x -> xhl (S x 2048: [hi|lo]) and xT1 (D x S, bf16 hi). grid (32,32,G).
// The lo plane is consumed only by the qkv GEMM; step 7 later reuses it
// to hold valb so [hi|valb] is contiguous for the fused output GEMM.
// ---------------------------------------------------------------------------
__global__ __launch_bounds__(256) void conv_x_kernel(
    const float* __restrict__ x, bf* __restrict__ xhl, bf* __restrict__ xT1)
{
    __shared__ float t[32][33];
    const int b = blockIdx.z;
    const int c0 = blockIdx.x * 32, r0 = blockIdx.y * 32;
    const int tx = threadIdx.x & 31, ty = threadIdx.x >> 5;  // ty 0..7
    const float* xb = x + (long)b * SS * DD;
    bf* xhlb = xhl + (long)b * SS * 2048;
#pragma unroll
    for (int p = 0; p < 4; ++p) {
        const int r = ty + 8 * p;
        const float v = xb[(long)(r0 + r) * DD + c0 + tx];
        t[r][tx] = v;
        bf hi, lo; split_bf16(v, hi, lo);
        xhlb[(long)(r0 + r) * 2048 + c0 + tx] = hi;
        xhlb[(long)(r0 + r) * 2048 + 1024 + c0 + tx] = lo;
    }
    __syncthreads();
#pragma unroll
    for (int p = 0; p < 4; ++p) {
        const int rr = ty + 8 * p;
        xT1[(long)b * DD * SS + (long)(c0 + rr) * SS + r0 + tx] =
            __float2bfloat16(t[tx][rr]);
    }
}

// ---------------------------------------------------------------------------
// In-place L2-normalize plane 3 of Q4 (even blocks, scaled by Wf[1]) / K4
// (odd blocks). grid = nrows*2, block 256.
// ---------------------------------------------------------------------------
__global__ __launch_bounds__(256) void l2norm_fuse_kernel(
    bf* __restrict__ q4, bf* __restrict__ k4, const float* __restrict__ Wf)
{
    __shared__ float red[4];
    const long row = blockIdx.x >> 1;
    const int half = blockIdx.x & 1;
    bf* p = (half ? k4 : q4) + row * 4096 + 3072;
    const int t = threadIdx.x;

    const u16x4 u = *reinterpret_cast<const u16x4*>(p + 4 * t);
    float v[4];
    float ss = 0.0f;
#pragma unroll
    for (int i = 0; i < 4; ++i) {
        unsigned short us = u[i];
        v[i] = __bfloat162float(*reinterpret_cast<const bf*>(&us));
        ss = fmaf(v[i], v[i], ss);
    }
    ss = blockReduceSum(ss, red);
    const float inv = 1.0f / fmaxf(sqrtf(ss), 1e-12f);
    const float scale = half ? inv : inv * Wf[1];   // fold Wf[1] into ctx_q
    u16x4 o;
#pragma unroll
    for (int i = 0; i < 4; ++i) {
        bf h = __float2bfloat16(v[i] * scale);
        o[i] = *reinterpret_cast<unsigned short*>(&h);
    }
    *reinterpret_cast<u16x4*>(p + 4 * t) = o;
}

// ---------------------------------------------------------------------------
// softmax -> mask -> L1 renorm, row 1024, fp32 in -> bf16 out. grid = nrows.
// ---------------------------------------------------------------------------
__global__ __launch_bounds__(256) void softmax_mask_kernel(
    const float* __restrict__ attn, const int* __restrict__ mask, bf* __restrict__ attn_bf)
{
    __shared__ float red[4];
    const long row = blockIdx.x;
    const float* p = attn + row * SS;
    const int* mrow = mask + row * SS;
    bf* o = attn_bf + row * SS;
    const int t = threadIdx.x;

    float v[4];
    int mv[4];
#pragma unroll
    for (int i = 0; i < 4; ++i) { v[i] = p[t + 256 * i]; mv[i] = mrow[t + 256 * i]; }
    float mx = fmaxf(fmaxf(v[0], v[1]), fmaxf(v[2], v[3]));
    mx = blockReduceMax(mx, red);

    float e[4];
    float s = 0.0f;
#pragma unroll
    for (int i = 0; i < 4; ++i) { e[i] = expf(v[i] - mx); s += e[i]; }
    s = blockReduceSum(s, red);

    float l1 = 0.0f;
#pragma unroll
    for (int i = 0; i < 4; ++i) { e[i] = mv[i] ? e[i] / s : 0.0f; l1 += e[i]; }
    l1 = blockReduceSum(l1, red);
    const float inv = 1.0f / fmaxf(l1, 1e-12f);
#pragma unroll
    for (int i = 0; i < 4; ++i) o[t + 256 * i] = __float2bfloat16(e[i] * inv);
}

// ---------------------------------------------------------------------------
extern "C" void kernel_launch(void* const* d_in, const int* in_sizes, int n_in,
                              void* d_out, int out_size, void* d_ws, size_t ws_size,
                              hipStream_t stream)
{
    const float* x    = (const float*)d_in[0];
    const int*   mask = (const int*)d_in[1];
    const float* Wqkv = (const float*)d_in[2];
    const float* bqkv = (const float*)d_in[3];
    const float* Wctx = (const float*)d_in[4];
    const float* bctx = (const float*)d_in[5];
    const float* Wf   = (const float*)d_in[6];
    const float* bfp  = (const float*)d_in[7];
    const float* Wo   = (const float*)d_in[8];
    const float* bo   = (const float*)d_in[9];
    float* out = (float*)d_out;

    const long SD = (long)SS * DD;                 // 1M elements per batch

    auto align_up = [](size_t v) { return (v + 255) & ~(size_t)255; };

    // Shared weight buffers
    const size_t sz_wq3  = 2048L * 3072 * 2;       // 12.6 MB [Whi|Whi|Wlo]
    const size_t sz_wctx = 2048L * 1024 * 2;       // 4.19 MB
    const size_t sz_wob  = 1024L * 2048 * 2;       // 4.19 MB full Wo
    const size_t SH = align_up(sz_wq3) + align_up(sz_wctx) + align_up(sz_wob);

    // Per-batch pooled regions (total 27262976 B):
    //   RX (4.19 MB): xhl [hi|lo]; lo plane becomes valb after step 7
    //   RT (2.10 MB): xT1
    //   RQ (8.39 MB): Q4 [Qhi|Qhi|Qlo|cq]; attnb aliases head after step 5
    //   RK (8.39 MB): K4 [Khi|Klo|Khi|ck]
    //   RY (4.19 MB): Y1 -> attn fp32 (Y1 dead after step 3)
    const size_t szXL = 1024L * 2048 * 2;
    const size_t szXT = 1024L * 1024 * 2;
    const size_t szQ4 = 1024L * 4096 * 2;
    const size_t szY  = 2048L * 1024 * 2;          // == 1024*1024*4 (attn fp32)
    const size_t PB = align_up(szXL) + align_up(szXT) + 2 * align_up(szQ4) +
                      align_up(szY);

    int G = 16;
    while (G > 1 && SH + (size_t)G * PB > ws_size) G >>= 1;

    char* p = (char*)d_ws;
    auto take = [&](size_t bytes) { char* r = p; p += align_up(bytes); return r; };
    bf* Wq3   = (bf*)take(sz_wq3);
    bf* Wctx1 = (bf*)take(sz_wctx);
    bf* Wob   = (bf*)take(sz_wob);
    char* RX = take((size_t)G * szXL);
    char* RT = take((size_t)G * szXT);
    char* RQ = take((size_t)G * szQ4);
    char* RK = take((size_t)G * szQ4);
    char* RY = take((size_t)G * szY);

    bf*    xhl   = (bf*)RX;                        // G x (1024 x 2048)
    bf*    xT1   = (bf*)RT;                        // G x (1024 x 1024)
    bf*    Q4    = (bf*)RQ;                        // G x (1024 x 4096)
    bf*    K4    = (bf*)RK;                        // G x (1024 x 4096)
    bf*    Y1    = (bf*)RY;                        // G x (2048 x 1024)
    float* attn  = (float*)RY;                     // G x (1024 x 1024) fp32
    bf*    attnb = (bf*)RQ;                        // G x (1024 x 1024)

    const dim3 blk(256);
    const dim3 blk5(512);
    const long sXL = 1024L * 2048;
    const long sAT = 1024L * 1024;
    const long sQ4 = 1024L * 4096;
    const long sY  = 2048L * 1024;

    // --- weight prep (once) ---
    prep_wqkv_kernel<<<dim3((2048L * 1024) / 256), blk, 0, stream>>>(Wqkv, Wq3);
    conv_kernel<<<dim3((2048L * 1024) / 256), blk, 0, stream>>>(Wctx, Wctx1, 1024, 1024, 2048L * 1024);
    conv_kernel<<<dim3((1024L * 2048) / 256), blk, 0, stream>>>(Wo, Wob, 2048, 2048, 1024L * 2048);

    for (int bc0 = 0; bc0 < BB; bc0 += G) {
        const float* xb = x + (long)bc0 * SD;
        const int M = G * 1024;                    // flattened rows this chunk

        // 0. x -> xhl ([hi|lo]), xT1
        conv_x_kernel<<<dim3(32, 32, G), blk, 0, stream>>>(xb, xhl, xT1);

        // 1. qkv = [xhi|xlo|(xhi)] * [Whi|Whi|Wlo]^T + bqkv  (K=3072, flat M,
        //    A wraps at 2048). Epilogue: Q planes (x Wf0) -> Q4, K -> K4.
        gemm256<2><<<dim3(2048 / 256, M / 256), blk5, 0, stream>>>(
            xhl, 0, 2048, 2048, Wq3, 0, 3072,
            nullptr, nullptr, Q4, K4, 0, 0, 3072,
            bqkv, Wf, 0, nullptr, 0);

        // 2. Y1 = Wctx * x^T  (NT via xT1), bf16 out (per batch)
        gemm256<1><<<dim3(1024 / 256, 2048 / 256, G), blk5, 0, stream>>>(
            Wctx1, 0, 1024, 1024, xT1, sAT, 1024,
            nullptr, Y1, nullptr, nullptr, sY, 1024, 1024,
            nullptr, nullptr, 0, nullptr, 0);

        // 3. ctx = xhi * Y1^T + bctx -> bf16 straight into Q4/K4 plane 3
        gemm256<3><<<dim3(2048 / 256, 1024 / 256, G), blk5, 0, stream>>>(
            xhl, sXL, 2048, 1024, Y1, sY, 1024,
            nullptr, nullptr, Q4, K4, sQ4, 0, 1024,
            bctx, nullptr, 0, nullptr, 0);

        // 4. L2-normalize plane 3 in place (q half scaled by Wf1)
        l2norm_fuse_kernel<<<dim3(G * 1024 * 2), blk, 0, stream>>>(Q4, K4, Wf);

        // 5. attn = Q4 * K4^T + bf   (K=4096: Wf0*(qhi*khi+qhi*klo+qlo*khi)
        //    + Wf1*(cq*ck), one pass, single fp32 write)
        gemm256<0><<<dim3(1024 / 256, 1024 / 256, G), blk5, 0, stream>>>(
            Q4, sQ4, 4096, 4096, K4, sQ4, 4096,
            attn, nullptr, nullptr, nullptr, sAT, 1024, 4096,
            nullptr, nullptr, 0, bfp, 0);

        // 6. softmax -> mask -> L1 renorm -> attnb
        softmax_mask_kernel<<<dim3(G * 1024), blk, 0, stream>>>(
            attn, mask + (long)bc0 * SS * SS, attnb);

        // 7. valb = attnb * x^T (NT via xT1), bf16 into xhl lo plane
        gemm256<1><<<dim3(1024 / 256, 1024 / 256, G), blk5, 0, stream>>>(
            attnb, sAT, 1024, 1024, xT1, sAT, 1024,
            nullptr, xhl + 1024, nullptr, nullptr, sXL, 2048, 1024,
            nullptr, nullptr, 0, nullptr, 0);

        // 8. out = [xhi|valb] * Wo^T + bo   (K=2048, flat M, single write)
        gemm256<0><<<dim3(1024 / 256, M / 256), blk5, 0, stream>>>(
            xhl, 0, 2048, 2048, Wob, 0, 2048,
            out + (long)bc0 * SD, nullptr, nullptr, nullptr, 0, 1024, 2048,
            bo, nullptr, 0, nullptr, 0);
    }
}

// Round 4
// 1012.633 us; speedup vs baseline: 1.5701x; 1.1359x over previous
//
#include <hip/hip_runtime.h>
#include <hip/hip_bf16.h>

// Problem constants
#define BB 16
#define SS 1024
#define DD 1024

typedef __hip_bfloat16 bf;
using s8v   = __attribute__((ext_vector_type(8))) short;
using f32x4 = __attribute__((ext_vector_type(4))) float;
using u16x4 = __attribute__((ext_vector_type(4))) unsigned short;

// Async global->LDS, 16 B per lane. LDS dest = wave-uniform base + lane*16.
__device__ __forceinline__ void gload16(const bf* g, unsigned short* l)
{
    __builtin_amdgcn_global_load_lds(
        (const __attribute__((address_space(1))) void*)g,
        (__attribute__((address_space(3))) void*)l,
        16, 0, 0);
}

// ---------------------------------------------------------------------------
// 256x256 8-phase bf16 NT GEMM (MFMA 16x16x32), BK=64, 8 waves (2Mx4N),
// 512 threads, 128 KiB LDS double-buffered, XOR-swizzled LDS via pre-swizzled
// global source. Counted vmcnt(6) pipeline (m201 shift-3 schedule). Plain
// s_barrier phases (no sched_barrier order-pinning - m141 lesson); compiler
// owns intra-phase scheduling; vmcnt asm keeps "memory" clobber for ordering.
//   C[m,n] (+)= alpha * sum_k A[m,k]*B[n,k]  (+ bias[n]) (+ addc)
// segA/segB: packed per-1024-segment source column offsets (units of 1024
//   elems, one byte per segment). Lets operands with duplicated logical
//   planes be stored deduplicated:  eff_col = (k & 1023) + 1024*byte[k>>10].
// EP=0: fp32 out (optional accumulate). EP=1: bf16 out.
// EP=2: QK split-write (flat rows, sC=0). v = acc + bias. col<1024 -> Q:
//   v*=Wf0(alpha), planes [hi|lo] row-stride 3072; col>=1024 -> K ditto.
//   (Plane 2 @2048 = ctx, filled later by EP=3 / l2norm.)
// EP=3: ctx split-write into plane 2 of qp/kp (z-stride sC).
// M,N multiples of 256, K multiple of 64 (NT >= 4). XCD-aware block swizzle
// (requires total blocks % 8 == 0 - true for all launches here).
// ---------------------------------------------------------------------------
template <int EP>
__global__ __launch_bounds__(512, 2) void gemm256(
    const bf* __restrict__ A, long sA, int lda, int segA,
    const bf* __restrict__ B, long sB, int ldb, int segB,
    float* __restrict__ C, bf* __restrict__ Cb,
    bf* __restrict__ qp, bf* __restrict__ kp,
    long sC, int ldc, int K,
    const float* __restrict__ bias,
    const float* __restrict__ alpha_ptr, int alpha_idx,
    const float* __restrict__ addc_ptr,
    int accumulate)
{
    // A: [2 dbuf][2 half][128 rows][64 cols] bf16 = 64 KB, then B same.
    __shared__ __align__(16) unsigned short lds[65536];
    unsigned short* Asm = lds;            // 4 * 8192 shorts
    unsigned short* Bsm = lds + 32768;

    // XCD-aware bijective swizzle: consecutive work ids -> same XCD.
    const int gx = gridDim.x, gy = gridDim.y;
    const int nwg = gx * gy * (int)gridDim.z;
    int lid = blockIdx.x + gx * (blockIdx.y + gy * blockIdx.z);
    lid = (lid & 7) * (nwg >> 3) + (lid >> 3);
    const int bx = lid % gx;
    const int rem = lid / gx;
    const int by = rem % gy;
    const int bz = rem / gy;

    const int tid = threadIdx.x;
    const int w = tid >> 6, l = tid & 63;
    const int wm = w >> 2, wn = w & 3;    // 2 x 4 wave grid
    const int lm = l & 15, quad = l >> 4;
    const int bh = wn >> 1;               // B half this wave reads
    const int bl0 = (wn & 1) * 64;        // B local row base within half

    const int m0 = by * 256, n0 = bx * 256;
    const bf* Ab = A + (long)bz * sA;
    const bf* Bb = B + (long)bz * sB;

    // Staging source map (pre-swizzled so linear LDS + swizzled read agree):
    // issue q of wave w -> half-local row = w*16 + q*8 + (l>>3),
    // 16B-chunk index = (l&7) ^ (l>>3)  -> element col = chunk*8.
    const int srow = w * 16 + (l >> 3);
    const int scol = ((l & 7) ^ (l >> 3)) << 3;
    const long aoff0 = (long)srow * lda + scol;
    const long aoff1 = (long)(srow + 8) * lda + scol;
    const long boff0 = (long)srow * ldb + scol;
    const long boff1 = (long)(srow + 8) * ldb + scol;
    const int ldst = w * 1024;            // shorts; +512 for issue q=1

    auto stageA = [&](int tt, int h) {
        const int kk = ((tt & 15) << 6) +
                       ((((unsigned)segA >> ((tt >> 4) << 3)) & 0xffu) << 10);
        const bf* g = Ab + (long)(m0 + h * 128) * lda + kk;
        unsigned short* d = Asm + (((tt & 1) << 1) + h) * 8192 + ldst;
        gload16(g + aoff0, d);
        gload16(g + aoff1, d + 512);
    };
    auto stageB = [&](int tt, int h) {
        const int kk = ((tt & 15) << 6) +
                       ((((unsigned)segB >> ((tt >> 4) << 3)) & 0xffu) << 10);
        const bf* g = Bb + (long)(n0 + h * 128) * ldb + kk;
        unsigned short* d = Bsm + (((tt & 1) << 1) + h) * 8192 + ldst;
        gload16(g + boff0, d);
        gload16(g + boff1, d + 512);
    };
    // Swizzled LDS fragment reads (rl&7 == lm&7 since frag rows are 16-aligned)
    auto rdA = [&](int d, int rl, int ks) -> s8v {
        const int off = rl * 64 + (((ks << 5) + (quad << 3)) ^ ((rl & 7) << 3));
        return *(const s8v*)(Asm + ((d << 1) + wm) * 8192 + off);
    };
    auto rdB = [&](int d, int bl, int ks) -> s8v {
        const int off = bl * 64 + (((ks << 5) + (quad << 3)) ^ ((bl & 7) << 3));
        return *(const s8v*)(Bsm + ((d << 1) + bh) * 8192 + off);
    };

    f32x4 acc[8][4];
#pragma unroll
    for (int i = 0; i < 8; ++i)
#pragma unroll
        for (int j = 0; j < 4; ++j)
            acc[i][j] = (f32x4){0.f, 0.f, 0.f, 0.f};

    const int NT = K >> 6;

    // Prologue: tile0 (4 HT), vmcnt(4); tile1 A-halves + Bh0 (3 HT); vmcnt(6).
    stageA(0, 0); stageA(0, 1); stageB(0, 0); stageB(0, 1);
    asm volatile("s_waitcnt vmcnt(4)" ::: "memory");
    stageA(1, 0); stageA(1, 1); stageB(1, 0);
    asm volatile("s_waitcnt vmcnt(6)" ::: "memory");
    __builtin_amdgcn_s_barrier();

    s8v a[8], b[4];
    for (int t = 0; t < NT; ++t) {
        const int d = t & 1;
        // ---- phase 1: Q1 = M0 x N0 (12 ds_reads; stage B(t+1)h1) ----
#pragma unroll
        for (int mf = 0; mf < 4; ++mf) {
            a[mf * 2]     = rdA(d, mf * 16 + lm, 0);
            a[mf * 2 + 1] = rdA(d, mf * 16 + lm, 1);
        }
#pragma unroll
        for (int nf = 0; nf < 2; ++nf) {
            b[nf * 2]     = rdB(d, bl0 + nf * 16 + lm, 0);
            b[nf * 2 + 1] = rdB(d, bl0 + nf * 16 + lm, 1);
        }
        if (t + 1 < NT) stageB(t + 1, 1);     // other dbuf: safe
        __builtin_amdgcn_s_barrier();
        __builtin_amdgcn_s_setprio(1);
#pragma unroll
        for (int mf = 0; mf < 4; ++mf)
#pragma unroll
            for (int nf = 0; nf < 2; ++nf) {
                acc[mf][nf] = __builtin_amdgcn_mfma_f32_16x16x32_bf16(a[mf*2],   b[nf*2],   acc[mf][nf], 0, 0, 0);
                acc[mf][nf] = __builtin_amdgcn_mfma_f32_16x16x32_bf16(a[mf*2+1], b[nf*2+1], acc[mf][nf], 0, 0, 0);
            }
        __builtin_amdgcn_s_setprio(0);
        __builtin_amdgcn_s_barrier();
        // ---- phase 2: Q2 = M0 x N1 (4 ds_reads; no stage) ----
#pragma unroll
        for (int nf = 0; nf < 2; ++nf) {
            b[nf * 2]     = rdB(d, bl0 + (nf + 2) * 16 + lm, 0);
            b[nf * 2 + 1] = rdB(d, bl0 + (nf + 2) * 16 + lm, 1);
        }
        __builtin_amdgcn_s_barrier();
        __builtin_amdgcn_s_setprio(1);
#pragma unroll
        for (int mf = 0; mf < 4; ++mf)
#pragma unroll
            for (int nf = 0; nf < 2; ++nf) {
                acc[mf][nf+2] = __builtin_amdgcn_mfma_f32_16x16x32_bf16(a[mf*2],   b[nf*2],   acc[mf][nf+2], 0, 0, 0);
                acc[mf][nf+2] = __builtin_amdgcn_mfma_f32_16x16x32_bf16(a[mf*2+1], b[nf*2+1], acc[mf][nf+2], 0, 0, 0);
            }
        __builtin_amdgcn_s_setprio(0);
        __builtin_amdgcn_s_barrier();
        // ---- phase 3: Q3 = M1 x N1 (8 ds_reads; stage A(t+2) both halves,
        //      issued AFTER the last A-reads of this buffer) ----
#pragma unroll
        for (int mf = 0; mf < 4; ++mf) {
            a[mf * 2]     = rdA(d, 64 + mf * 16 + lm, 0);
            a[mf * 2 + 1] = rdA(d, 64 + mf * 16 + lm, 1);
        }
        if (t + 2 < NT) { stageA(t + 2, 0); stageA(t + 2, 1); }
        __builtin_amdgcn_s_barrier();
        __builtin_amdgcn_s_setprio(1);
#pragma unroll
        for (int mf = 0; mf < 4; ++mf)
#pragma unroll
            for (int nf = 0; nf < 2; ++nf) {
                acc[mf+4][nf+2] = __builtin_amdgcn_mfma_f32_16x16x32_bf16(a[mf*2],   b[nf*2],   acc[mf+4][nf+2], 0, 0, 0);
                acc[mf+4][nf+2] = __builtin_amdgcn_mfma_f32_16x16x32_bf16(a[mf*2+1], b[nf*2+1], acc[mf+4][nf+2], 0, 0, 0);
            }
        __builtin_amdgcn_s_setprio(0);
        __builtin_amdgcn_s_barrier();
        // ---- phase 4: Q4 = M1 x N0 (4 ds_reads; stage B(t+2)h0; counted
        //      vmcnt, never 0 until drain) ----
#pragma unroll
        for (int nf = 0; nf < 2; ++nf) {
            b[nf * 2]     = rdB(d, bl0 + nf * 16 + lm, 0);
            b[nf * 2 + 1] = rdB(d, bl0 + nf * 16 + lm, 1);
        }
        if (t + 2 < NT) {
            stageB(t + 2, 0);
            asm volatile("s_waitcnt vmcnt(6)" ::: "memory");
        } else {
            asm volatile("s_waitcnt vmcnt(0)" ::: "memory");
        }
        __builtin_amdgcn_s_barrier();
        __builtin_amdgcn_s_setprio(1);
#pragma unroll
        for (int mf = 0; mf < 4; ++mf)
#pragma unroll
            for (int nf = 0; nf < 2; ++nf) {
                acc[mf+4][nf] = __builtin_amdgcn_mfma_f32_16x16x32_bf16(a[mf*2],   b[nf*2],   acc[mf+4][nf], 0, 0, 0);
                acc[mf+4][nf] = __builtin_amdgcn_mfma_f32_16x16x32_bf16(a[mf*2+1], b[nf*2+1], acc[mf+4][nf], 0, 0, 0);
            }
        __builtin_amdgcn_s_setprio(0);
        __builtin_amdgcn_s_barrier();
    }

    // ------------------------------- epilogue -------------------------------
    const float alpha = alpha_ptr ? alpha_ptr[alpha_idx] : 1.0f;
    const float addc  = addc_ptr ? addc_ptr[0] : 0.0f;
    float* Cp = C ? C + (long)bz * sC : nullptr;
    bf* Cbp = (EP == 1) ? Cb + (long)bz * sC : nullptr;
    bf* qpz = (EP == 2 || EP == 3) ? qp + (long)bz * sC : nullptr;
    bf* kpz = (EP == 2 || EP == 3) ? kp + (long)bz * sC : nullptr;

#pragma unroll
    for (int mf = 0; mf < 8; ++mf) {
#pragma unroll
        for (int nf = 0; nf < 4; ++nf) {
            const int cidx = n0 + wn * 64 + nf * 16 + lm;
            const float bv = bias ? bias[cidx] : 0.0f;
            const long rbase = m0 + wm * 128 + mf * 16 + quad * 4;
#pragma unroll
            for (int r = 0; r < 4; ++r) {
                const long row = rbase + r;
                if (EP == 2) {
                    float v = acc[mf][nf][r] + bv;
                    if (cidx < 1024) {
                        v *= alpha;      // fold Wf[0] into Q planes
                        bf hi = __float2bfloat16(v);
                        bf lo = __float2bfloat16(v - __bfloat162float(hi));
                        qpz[row * 3072 + cidx] = hi;
                        qpz[row * 3072 + 1024 + cidx] = lo;
                    } else {
                        const int c = cidx - 1024;
                        bf hi = __float2bfloat16(v);
                        bf lo = __float2bfloat16(v - __bfloat162float(hi));
                        kpz[row * 3072 + c] = hi;
                        kpz[row * 3072 + 1024 + c] = lo;
                    }
                } else if (EP == 3) {
                    const float v = acc[mf][nf][r] + bv;
                    const bf h = __float2bfloat16(v);
                    if (cidx < 1024) qpz[row * 3072 + 2048 + cidx] = h;
                    else             kpz[row * 3072 + 2048 + (cidx - 1024)] = h;
                } else {
                    float v = alpha * acc[mf][nf][r] + addc + bv;
                    const long off = row * (long)ldc + cidx;
                    if (EP == 1) {
                        Cbp[off] = __float2bfloat16(v);
                    } else {
                        if (accumulate) v += Cp[off];
                        Cp[off] = v;
                    }
                }
            }
        }
    }
}

// ---------------------------------------------------------------------------
// Block reductions (256 threads = 4 waves of 64)
// ---------------------------------------------------------------------------
__device__ inline float blockReduceSum(float v, float* red)
{
#pragma unroll
    for (int off = 32; off > 0; off >>= 1) v += __shfl_xor(v, off, 64);
    __syncthreads();
    if ((threadIdx.x & 63) == 0) red[threadIdx.x >> 6] = v;
    __syncthreads();
    return red[0] + red[1] + red[2] + red[3];
}

__device__ inline float blockReduceMax(float v, float* red)
{
#pragma unroll
    for (int off = 32; off > 0; off >>= 1) v = fmaxf(v, __shfl_xor(v, off, 64));
    __syncthreads();
    if ((threadIdx.x & 63) == 0) red[threadIdx.x >> 6] = v;
    __syncthreads();
    return fmaxf(fmaxf(red[0], red[1]), fmaxf(red[2], red[3]));
}

__device__ inline void split_bf16(float v, bf& hi, bf& lo)
{
    hi = __float2bfloat16(v);
    lo = __float2bfloat16(v - __bfloat162float(hi));
}

// ---------------------------------------------------------------------------
// Weight prep (once per launch)
// ---------------------------------------------------------------------------
// Wqkv (2048x1024 fp32) -> Wq2 (2048x2048: [Whi|Wlo]). The qkv GEMM's segB
// table {0,0,1} re-reads Whi for the xlo segment.
__global__ __launch_bounds__(256) void prep_wqkv_kernel(
    const float* __restrict__ W, bf* __restrict__ wq2)
{
    long i = (long)blockIdx.x * 256 + threadIdx.x;   // 2048*1024 threads
    long r = i >> 10; int c = (int)(i & 1023);
    bf hi, lo; split_bf16(W[i], hi, lo);
    wq2[r * 2048 + c] = hi;
    wq2[r * 2048 + 1024 + c] = lo;
}

// plain fp32 -> bf16 with source stride
__global__ __launch_bounds__(256) void conv_kernel(
    const float* __restrict__ src, bf* __restrict__ dst, int cols, int src_ld, long n)
{
    long i = (long)blockIdx.x * 256 + threadIdx.x;
    if (i >= n) return;
    long r = i / cols; int c = (int)(i % cols);
    dst[i] = __float2bfloat16(src[r * src_ld + c]);
}

// ---------------------------------------------------------------------------
// x -> xhl (S x 2048: [hi|lo]) and xT1 (D x S, bf16 hi). grid (32,32,G).
// The lo plane is consumed only by the qkv GEMM; step 7 later reuses it
// to hold valb so [hi|valb] is contiguous for the fused output GEMM.
// ---------------------------------------------------------------------------
__global__ __launch_bounds__(256) void conv_x_kernel(
    const float* __restrict__ x, bf* __restrict__ xhl, bf* __restrict__ xT1)
{
    __shared__ float t[32][33];
    const int b = blockIdx.z;
    const int c0 = blockIdx.x * 32, r0 = blockIdx.y * 32;
    const int tx = threadIdx.x & 31, ty = threadIdx.x >> 5;  // ty 0..7
    const float* xb = x + (long)b * SS * DD;
    bf* xhlb = xhl + (long)b * SS * 2048;
#pragma unroll
    for (int p = 0; p < 4; ++p) {
        const int r = ty + 8 * p;
        const float v = xb[(long)(r0 + r) * DD + c0 + tx];
        t[r][tx] = v;
        bf hi, lo; split_bf16(v, hi, lo);
        xhlb[(long)(r0 + r) * 2048 + c0 + tx] = hi;
        xhlb[(long)(r0 + r) * 2048 + 1024 + c0 + tx] = lo;
    }
    __syncthreads();
#pragma unroll
    for (int p = 0; p < 4; ++p) {
        const int rr = ty + 8 * p;
        xT1[(long)b * DD * SS + (long)(c0 + rr) * SS + r0 + tx] =
            __float2bfloat16(t[tx][rr]);
    }
}

// ---------------------------------------------------------------------------
// In-place L2-normalize plane 2 (offset 2048, row stride 3072) of Q3 (even
// blocks, scaled by Wf[1]) / K3 (odd blocks). grid = nrows*2, block 256.
// ---------------------------------------------------------------------------
__global__ __launch_bounds__(256) void l2norm_fuse_kernel(
    bf* __restrict__ q3, bf* __restrict__ k3, const float* __restrict__ Wf)
{
    __shared__ float red[4];
    const long row = blockIdx.x >> 1;
    const int half = blockIdx.x & 1;
    bf* p = (half ? k3 : q3) + row * 3072 + 2048;
    const int t = threadIdx.x;

    const u16x4 u = *reinterpret_cast<const u16x4*>(p + 4 * t);
    float v[4];
    float ss = 0.0f;
#pragma unroll
    for (int i = 0; i < 4; ++i) {
        unsigned short us = u[i];
        v[i] = __bfloat162float(*reinterpret_cast<const bf*>(&us));
        ss = fmaf(v[i], v[i], ss);
    }
    ss = blockReduceSum(ss, red);
    const float inv = 1.0f / fmaxf(sqrtf(ss), 1e-12f);
    const float scale = half ? inv : inv * Wf[1];   // fold Wf[1] into ctx_q
    u16x4 o;
#pragma unroll
    for (int i = 0; i < 4; ++i) {
        bf h = __float2bfloat16(v[i] * scale);
        o[i] = *reinterpret_cast<unsigned short*>(&h);
    }
    *reinterpret_cast<u16x4*>(p + 4 * t) = o;
}

// ---------------------------------------------------------------------------
// softmax -> mask -> L1 renorm, row 1024, fp32 in -> bf16 out. grid = nrows.
// ---------------------------------------------------------------------------
__global__ __launch_bounds__(256) void softmax_mask_kernel(
    const float* __restrict__ attn, const int* __restrict__ mask, bf* __restrict__ attn_bf)
{
    __shared__ float red[4];
    const long row = blockIdx.x;
    const float* p = attn + row * SS;
    const int* mrow = mask + row * SS;
    bf* o = attn_bf + row * SS;
    const int t = threadIdx.x;

    float v[4];
    int mv[4];
#pragma unroll
    for (int i = 0; i < 4; ++i) { v[i] = p[t + 256 * i]; mv[i] = mrow[t + 256 * i]; }
    float mx = fmaxf(fmaxf(v[0], v[1]), fmaxf(v[2], v[3]));
    mx = blockReduceMax(mx, red);

    float e[4];
    float s = 0.0f;
#pragma unroll
    for (int i = 0; i < 4; ++i) { e[i] = expf(v[i] - mx); s += e[i]; }
    s = blockReduceSum(s, red);

    float l1 = 0.0f;
#pragma unroll
    for (int i = 0; i < 4; ++i) { e[i] = mv[i] ? e[i] / s : 0.0f; l1 += e[i]; }
    l1 = blockReduceSum(l1, red);
    const float inv = 1.0f / fmaxf(l1, 1e-12f);
#pragma unroll
    for (int i = 0; i < 4; ++i) o[t + 256 * i] = __float2bfloat16(e[i] * inv);
}

// ---------------------------------------------------------------------------
extern "C" void kernel_launch(void* const* d_in, const int* in_sizes, int n_in,
                              void* d_out, int out_size, void* d_ws, size_t ws_size,
                              hipStream_t stream)
{
    const float* x    = (const float*)d_in[0];
    const int*   mask = (const int*)d_in[1];
    const float* Wqkv = (const float*)d_in[2];
    const float* bqkv = (const float*)d_in[3];
    const float* Wctx = (const float*)d_in[4];
    const float* bctx = (const float*)d_in[5];
    const float* Wf   = (const float*)d_in[6];
    const float* bfp  = (const float*)d_in[7];
    const float* Wo   = (const float*)d_in[8];
    const float* bo   = (const float*)d_in[9];
    float* out = (float*)d_out;

    const long SD = (long)SS * DD;                 // 1M elements per batch

    auto align_up = [](size_t v) { return (v + 255) & ~(size_t)255; };

    // Shared weight buffers
    const size_t sz_wq2  = 2048L * 2048 * 2;       // 8.39 MB [Whi|Wlo]
    const size_t sz_wctx = 2048L * 1024 * 2;       // 4.19 MB
    const size_t sz_wob  = 1024L * 2048 * 2;       // 4.19 MB full Wo
    const size_t SH = align_up(sz_wq2) + align_up(sz_wctx) + align_up(sz_wob);

    // Per-batch pooled regions (total ~23.1 MB):
    //   RX (4.19 MB): xhl [hi|lo]; lo plane becomes valb after step 7
    //   RT (2.10 MB): xT1
    //   RQ (6.29 MB): Q3 [Qhi|Qlo|cq]; attnb aliases head after step 5
    //   RK (6.29 MB): K3 [Khi|Klo|ck]
    //   RY (4.19 MB): Y1 -> attn fp32 (Y1 dead after step 3)
    const size_t szXL = 1024L * 2048 * 2;
    const size_t szXT = 1024L * 1024 * 2;
    const size_t szQ3 = 1024L * 3072 * 2;
    const size_t szY  = 2048L * 1024 * 2;          // == 1024*1024*4 (attn fp32)
    const size_t PB = align_up(szXL) + align_up(szXT) + 2 * align_up(szQ3) +
                      align_up(szY);

    int G = 16;
    while (G > 1 && SH + (size_t)G * PB > ws_size) G >>= 1;

    char* p = (char*)d_ws;
    auto take = [&](size_t bytes) { char* r = p; p += align_up(bytes); return r; };
    bf* Wq2   = (bf*)take(sz_wq2);
    bf* Wctx1 = (bf*)take(sz_wctx);
    bf* Wob   = (bf*)take(sz_wob);
    char* RX = take((size_t)G * szXL);
    char* RT = take((size_t)G * szXT);
    char* RQ = take((size_t)G * szQ3);
    char* RK = take((size_t)G * szQ3);
    char* RY = take((size_t)G * szY);

    bf*    xhl   = (bf*)RX;                        // G x (1024 x 2048)
    bf*    xT1   = (bf*)RT;                        // G x (1024 x 1024)
    bf*    Q3    = (bf*)RQ;                        // G x (1024 x 3072)
    bf*    K3    = (bf*)RK;                        // G x (1024 x 3072)
    bf*    Y1    = (bf*)RY;                        // G x (2048 x 1024)
    float* attn  = (float*)RY;                     // G x (1024 x 1024) fp32
    bf*    attnb = (bf*)RQ;                        // G x (1024 x 1024)

    const dim3 blk(256);
    const dim3 blk5(512);
    const long sXL = 1024L * 2048;
    const long sAT = 1024L * 1024;
    const long sQ3 = 1024L * 3072;
    const long sY  = 2048L * 1024;

    // Segment tables (byte s = source col offset / 1024 for k in segment s)
    const int segQKV_A = 0x0100;      // [xhi|xlo|(xhi)]
    const int segQKV_B = 0x010000;    // [Whi|(Whi)|Wlo]
    const int segATT_A = 0x02010000;  // [Qhi|(Qhi)|Qlo|cq]
    const int segATT_B = 0x02000100;  // [Khi|Klo|(Khi)|ck]
    const int segOUT   = 0x0100;      // plain 2048-wide

    // --- weight prep (once) ---
    prep_wqkv_kernel<<<dim3((2048L * 1024) / 256), blk, 0, stream>>>(Wqkv, Wq2);
    conv_kernel<<<dim3((2048L * 1024) / 256), blk, 0, stream>>>(Wctx, Wctx1, 1024, 1024, 2048L * 1024);
    conv_kernel<<<dim3((1024L * 2048) / 256), blk, 0, stream>>>(Wo, Wob, 2048, 2048, 1024L * 2048);

    for (int bc0 = 0; bc0 < BB; bc0 += G) {
        const float* xb = x + (long)bc0 * SD;
        const int M = G * 1024;                    // flattened rows this chunk

        // 0. x -> xhl ([hi|lo]), xT1
        conv_x_kernel<<<dim3(32, 32, G), blk, 0, stream>>>(xb, xhl, xT1);

        // 1. qkv = xhi*Whi + xlo*Whi + xhi*Wlo + bqkv  (K=3072 via segment
        //    tables, flat M). Epilogue: Q planes (x Wf0) -> Q3, K -> K3.
        gemm256<2><<<dim3(2048 / 256, M / 256), blk5, 0, stream>>>(
            xhl, 0, 2048, segQKV_A, Wq2, 0, 2048, segQKV_B,
            nullptr, nullptr, Q3, K3, 0, 0, 3072,
            bqkv, Wf, 0, nullptr, 0);

        // 2. Y1 = Wctx * x^T  (NT via xT1), bf16 out (per batch)
        gemm256<1><<<dim3(1024 / 256, 2048 / 256, G), blk5, 0, stream>>>(
            Wctx1, 0, 1024, 0, xT1, sAT, 1024, 0,
            nullptr, Y1, nullptr, nullptr, sY, 1024, 1024,
            nullptr, nullptr, 0, nullptr, 0);

        // 3. ctx = xhi * Y1^T + bctx -> bf16 straight into Q3/K3 plane 2
        gemm256<3><<<dim3(2048 / 256, 1024 / 256, G), blk5, 0, stream>>>(
            xhl, sXL, 2048, 0, Y1, sY, 1024, 0,
            nullptr, nullptr, Q3, K3, sQ3, 0, 1024,
            bctx, nullptr, 0, nullptr, 0);

        // 4. L2-normalize plane 2 in place (q half scaled by Wf1)
        l2norm_fuse_kernel<<<dim3(G * 1024 * 2), blk, 0, stream>>>(Q3, K3, Wf);

        // 5. attn = Q3 * K3^T + bf   (K=4096 via segment tables:
        //    Wf0*(qhi*khi+qhi*klo+qlo*khi) + Wf1*(cq*ck), single fp32 write)
        gemm256<0><<<dim3(1024 / 256, 1024 / 256, G), blk5, 0, stream>>>(
            Q3, sQ3, 3072, segATT_A, K3, sQ3, 3072, segATT_B,
            attn, nullptr, nullptr, nullptr, sAT, 1024, 4096,
            nullptr, nullptr, 0, bfp, 0);

        // 6. softmax -> mask -> L1 renorm -> attnb
        softmax_mask_kernel<<<dim3(G * 1024), blk, 0, stream>>>(
            attn, mask + (long)bc0 * SS * SS, attnb);

        // 7. valb = attnb * x^T (NT via xT1), bf16 into xhl lo plane
        gemm256<1><<<dim3(1024 / 256, 1024 / 256, G), blk5, 0, stream>>>(
            attnb, sAT, 1024, 0, xT1, sAT, 1024, 0,
            nullptr, xhl + 1024, nullptr, nullptr, sXL, 2048, 1024,
            nullptr, nullptr, 0, nullptr, 0);

        // 8. out = [xhi|valb] * Wo^T + bo   (K=2048, flat M, single write)
        gemm256<0><<<dim3(1024 / 256, M / 256), blk5, 0, stream>>>(
            xhl, 0, 2048, segOUT, Wob, 0, 2048, segOUT,
            out + (long)bc0 * SD, nullptr, nullptr, nullptr, 0, 1024, 2048,
            bo, nullptr, 0, nullptr, 0);
    }
}

// Round 5
// 1003.953 us; speedup vs baseline: 1.5837x; 1.0086x over previous
//
#include <hip/hip_runtime.h>
#include <hip/hip_bf16.h>

// Problem constants
#define BB 16
#define SS 1024
#define DD 1024

typedef __hip_bfloat16 bf;
using s8v   = __attribute__((ext_vector_type(8))) short;
using f32x4 = __attribute__((ext_vector_type(4))) float;
using u16x4 = __attribute__((ext_vector_type(4))) unsigned short;
using u16x8 = __attribute__((ext_vector_type(8))) unsigned short;
using i32x4 = __attribute__((ext_vector_type(4))) int;

// Async global->LDS, 16 B per lane. LDS dest = wave-uniform base + lane*16.
__device__ __forceinline__ void gload16(const bf* g, unsigned short* l)
{
    __builtin_amdgcn_global_load_lds(
        (const __attribute__((address_space(1))) void*)g,
        (__attribute__((address_space(3))) void*)l,
        16, 0, 0);
}

// ---------------------------------------------------------------------------
// 256x256 8-phase bf16 NT GEMM (MFMA 16x16x32), BK=64, 8 waves (2Mx4N),
// 512 threads, 128 KiB LDS double-buffered, XOR-swizzled LDS via pre-swizzled
// global source. Counted vmcnt(6) pipeline (m201 shift-3 schedule). Plain
// s_barrier phases; compiler owns intra-phase scheduling.
//   C[m,n] (+)= alpha * sum_k A[m,k]*B[n,k]  (+ bias[n]) (+ addc)
// segA/segB: packed per-1024-segment source column offsets (units of 1024
//   elems, one byte per segment): eff_col = (k & 1023) + 1024*byte[k>>10].
// EP=0: fp32 out (optional accumulate). EP=1: bf16 out.
// EP=2: QK split-write (flat rows, sC=0). v = acc + bias. col<1024 -> Q:
//   v*=Wf0(alpha), planes [hi|lo] row-stride 3072; col>=1024 -> K ditto.
// EP=3: ctx split-write into plane 2 of qp/kp (z-stride sC).
// M,N multiples of 256, K multiple of 64 (NT >= 4). XCD-aware block swizzle
// (requires total blocks % 8 == 0 - true for all launches here).
// ---------------------------------------------------------------------------
template <int EP>
__global__ __launch_bounds__(512, 2) void gemm256(
    const bf* __restrict__ A, long sA, int lda, int segA,
    const bf* __restrict__ B, long sB, int ldb, int segB,
    float* __restrict__ C, bf* __restrict__ Cb,
    bf* __restrict__ qp, bf* __restrict__ kp,
    long sC, int ldc, int K,
    const float* __restrict__ bias,
    const float* __restrict__ alpha_ptr, int alpha_idx,
    const float* __restrict__ addc_ptr,
    int accumulate)
{
    // A: [2 dbuf][2 half][128 rows][64 cols] bf16 = 64 KB, then B same.
    __shared__ __align__(16) unsigned short lds[65536];
    unsigned short* Asm = lds;            // 4 * 8192 shorts
    unsigned short* Bsm = lds + 32768;

    // XCD-aware bijective swizzle: consecutive work ids -> same XCD.
    const int gx = gridDim.x, gy = gridDim.y;
    const int nwg = gx * gy * (int)gridDim.z;
    int lid = blockIdx.x + gx * (blockIdx.y + gy * blockIdx.z);
    lid = (lid & 7) * (nwg >> 3) + (lid >> 3);
    const int bx = lid % gx;
    const int rem = lid / gx;
    const int by = rem % gy;
    const int bz = rem / gy;

    const int tid = threadIdx.x;
    const int w = tid >> 6, l = tid & 63;
    const int wm = w >> 2, wn = w & 3;    // 2 x 4 wave grid
    const int lm = l & 15, quad = l >> 4;
    const int bh = wn >> 1;               // B half this wave reads
    const int bl0 = (wn & 1) * 64;        // B local row base within half

    const int m0 = by * 256, n0 = bx * 256;
    const bf* Ab = A + (long)bz * sA;
    const bf* Bb = B + (long)bz * sB;

    // Staging source map (pre-swizzled so linear LDS + swizzled read agree):
    // issue q of wave w -> half-local row = w*16 + q*8 + (l>>3),
    // 16B-chunk index = (l&7) ^ (l>>3)  -> element col = chunk*8.
    const int srow = w * 16 + (l >> 3);
    const int scol = ((l & 7) ^ (l >> 3)) << 3;
    const long aoff0 = (long)srow * lda + scol;
    const long aoff1 = (long)(srow + 8) * lda + scol;
    const long boff0 = (long)srow * ldb + scol;
    const long boff1 = (long)(srow + 8) * ldb + scol;
    const int ldst = w * 1024;            // shorts; +512 for issue q=1

    auto stageA = [&](int tt, int h) {
        const int kk = ((tt & 15) << 6) +
                       ((((unsigned)segA >> ((tt >> 4) << 3)) & 0xffu) << 10);
        const bf* g = Ab + (long)(m0 + h * 128) * lda + kk;
        unsigned short* d = Asm + (((tt & 1) << 1) + h) * 8192 + ldst;
        gload16(g + aoff0, d);
        gload16(g + aoff1, d + 512);
    };
    auto stageB = [&](int tt, int h) {
        const int kk = ((tt & 15) << 6) +
                       ((((unsigned)segB >> ((tt >> 4) << 3)) & 0xffu) << 10);
        const bf* g = Bb + (long)(n0 + h * 128) * ldb + kk;
        unsigned short* d = Bsm + (((tt & 1) << 1) + h) * 8192 + ldst;
        gload16(g + boff0, d);
        gload16(g + boff1, d + 512);
    };
    // Swizzled LDS fragment reads (rl&7 == lm&7 since frag rows are 16-aligned)
    auto rdA = [&](int d, int rl, int ks) -> s8v {
        const int off = rl * 64 + (((ks << 5) + (quad << 3)) ^ ((rl & 7) << 3));
        return *(const s8v*)(Asm + ((d << 1) + wm) * 8192 + off);
    };
    auto rdB = [&](int d, int bl, int ks) -> s8v {
        const int off = bl * 64 + (((ks << 5) + (quad << 3)) ^ ((bl & 7) << 3));
        return *(const s8v*)(Bsm + ((d << 1) + bh) * 8192 + off);
    };

    f32x4 acc[8][4];
#pragma unroll
    for (int i = 0; i < 8; ++i)
#pragma unroll
        for (int j = 0; j < 4; ++j)
            acc[i][j] = (f32x4){0.f, 0.f, 0.f, 0.f};

    const int NT = K >> 6;

    // Prologue: tile0 (4 HT), vmcnt(4); tile1 A-halves + Bh0 (3 HT); vmcnt(6).
    stageA(0, 0); stageA(0, 1); stageB(0, 0); stageB(0, 1);
    asm volatile("s_waitcnt vmcnt(4)" ::: "memory");
    stageA(1, 0); stageA(1, 1); stageB(1, 0);
    asm volatile("s_waitcnt vmcnt(6)" ::: "memory");
    __builtin_amdgcn_s_barrier();

    s8v a[8], b[4];
    for (int t = 0; t < NT; ++t) {
        const int d = t & 1;
        // ---- phase 1: Q1 = M0 x N0 (12 ds_reads; stage B(t+1)h1) ----
#pragma unroll
        for (int mf = 0; mf < 4; ++mf) {
            a[mf * 2]     = rdA(d, mf * 16 + lm, 0);
            a[mf * 2 + 1] = rdA(d, mf * 16 + lm, 1);
        }
#pragma unroll
        for (int nf = 0; nf < 2; ++nf) {
            b[nf * 2]     = rdB(d, bl0 + nf * 16 + lm, 0);
            b[nf * 2 + 1] = rdB(d, bl0 + nf * 16 + lm, 1);
        }
        if (t + 1 < NT) stageB(t + 1, 1);     // other dbuf: safe
        __builtin_amdgcn_s_barrier();
        __builtin_amdgcn_s_setprio(1);
#pragma unroll
        for (int mf = 0; mf < 4; ++mf)
#pragma unroll
            for (int nf = 0; nf < 2; ++nf) {
                acc[mf][nf] = __builtin_amdgcn_mfma_f32_16x16x32_bf16(a[mf*2],   b[nf*2],   acc[mf][nf], 0, 0, 0);
                acc[mf][nf] = __builtin_amdgcn_mfma_f32_16x16x32_bf16(a[mf*2+1], b[nf*2+1], acc[mf][nf], 0, 0, 0);
            }
        __builtin_amdgcn_s_setprio(0);
        __builtin_amdgcn_s_barrier();
        // ---- phase 2: Q2 = M0 x N1 (4 ds_reads; no stage) ----
#pragma unroll
        for (int nf = 0; nf < 2; ++nf) {
            b[nf * 2]     = rdB(d, bl0 + (nf + 2) * 16 + lm, 0);
            b[nf * 2 + 1] = rdB(d, bl0 + (nf + 2) * 16 + lm, 1);
        }
        __builtin_amdgcn_s_barrier();
        __builtin_amdgcn_s_setprio(1);
#pragma unroll
        for (int mf = 0; mf < 4; ++mf)
#pragma unroll
            for (int nf = 0; nf < 2; ++nf) {
                acc[mf][nf+2] = __builtin_amdgcn_mfma_f32_16x16x32_bf16(a[mf*2],   b[nf*2],   acc[mf][nf+2], 0, 0, 0);
                acc[mf][nf+2] = __builtin_amdgcn_mfma_f32_16x16x32_bf16(a[mf*2+1], b[nf*2+1], acc[mf][nf+2], 0, 0, 0);
            }
        __builtin_amdgcn_s_setprio(0);
        __builtin_amdgcn_s_barrier();
        // ---- phase 3: Q3 = M1 x N1 (8 ds_reads; stage A(t+2) both halves,
        //      issued AFTER the last A-reads of this buffer) ----
#pragma unroll
        for (int mf = 0; mf < 4; ++mf) {
            a[mf * 2]     = rdA(d, 64 + mf * 16 + lm, 0);
            a[mf * 2 + 1] = rdA(d, 64 + mf * 16 + lm, 1);
        }
        if (t + 2 < NT) { stageA(t + 2, 0); stageA(t + 2, 1); }
        __builtin_amdgcn_s_barrier();
        __builtin_amdgcn_s_setprio(1);
#pragma unroll
        for (int mf = 0; mf < 4; ++mf)
#pragma unroll
            for (int nf = 0; nf < 2; ++nf) {
                acc[mf+4][nf+2] = __builtin_amdgcn_mfma_f32_16x16x32_bf16(a[mf*2],   b[nf*2],   acc[mf+4][nf+2], 0, 0, 0);
                acc[mf+4][nf+2] = __builtin_amdgcn_mfma_f32_16x16x32_bf16(a[mf*2+1], b[nf*2+1], acc[mf+4][nf+2], 0, 0, 0);
            }
        __builtin_amdgcn_s_setprio(0);
        __builtin_amdgcn_s_barrier();
        // ---- phase 4: Q4 = M1 x N0 (4 ds_reads; stage B(t+2)h0; counted
        //      vmcnt, never 0 until drain) ----
#pragma unroll
        for (int nf = 0; nf < 2; ++nf) {
            b[nf * 2]     = rdB(d, bl0 + nf * 16 + lm, 0);
            b[nf * 2 + 1] = rdB(d, bl0 + nf * 16 + lm, 1);
        }
        if (t + 2 < NT) {
            stageB(t + 2, 0);
            asm volatile("s_waitcnt vmcnt(6)" ::: "memory");
        } else {
            asm volatile("s_waitcnt vmcnt(0)" ::: "memory");
        }
        __builtin_amdgcn_s_barrier();
        __builtin_amdgcn_s_setprio(1);
#pragma unroll
        for (int mf = 0; mf < 4; ++mf)
#pragma unroll
            for (int nf = 0; nf < 2; ++nf) {
                acc[mf+4][nf] = __builtin_amdgcn_mfma_f32_16x16x32_bf16(a[mf*2],   b[nf*2],   acc[mf+4][nf], 0, 0, 0);
                acc[mf+4][nf] = __builtin_amdgcn_mfma_f32_16x16x32_bf16(a[mf*2+1], b[nf*2+1], acc[mf+4][nf], 0, 0, 0);
            }
        __builtin_amdgcn_s_setprio(0);
        __builtin_amdgcn_s_barrier();
    }

    // ------------------------------- epilogue -------------------------------
    const float alpha = alpha_ptr ? alpha_ptr[alpha_idx] : 1.0f;
    const float addc  = addc_ptr ? addc_ptr[0] : 0.0f;
    float* Cp = C ? C + (long)bz * sC : nullptr;
    bf* Cbp = (EP == 1) ? Cb + (long)bz * sC : nullptr;
    bf* qpz = (EP == 2 || EP == 3) ? qp + (long)bz * sC : nullptr;
    bf* kpz = (EP == 2 || EP == 3) ? kp + (long)bz * sC : nullptr;

#pragma unroll
    for (int mf = 0; mf < 8; ++mf) {
#pragma unroll
        for (int nf = 0; nf < 4; ++nf) {
            const int cidx = n0 + wn * 64 + nf * 16 + lm;
            const float bv = bias ? bias[cidx] : 0.0f;
            const long rbase = m0 + wm * 128 + mf * 16 + quad * 4;
#pragma unroll
            for (int r = 0; r < 4; ++r) {
                const long row = rbase + r;
                if (EP == 2) {
                    float v = acc[mf][nf][r] + bv;
                    if (cidx < 1024) {
                        v *= alpha;      // fold Wf[0] into Q planes
                        bf hi = __float2bfloat16(v);
                        bf lo = __float2bfloat16(v - __bfloat162float(hi));
                        qpz[row * 3072 + cidx] = hi;
                        qpz[row * 3072 + 1024 + cidx] = lo;
                    } else {
                        const int c = cidx - 1024;
                        bf hi = __float2bfloat16(v);
                        bf lo = __float2bfloat16(v - __bfloat162float(hi));
                        kpz[row * 3072 + c] = hi;
                        kpz[row * 3072 + 1024 + c] = lo;
                    }
                } else if (EP == 3) {
                    const float v = acc[mf][nf][r] + bv;
                    const bf h = __float2bfloat16(v);
                    if (cidx < 1024) qpz[row * 3072 + 2048 + cidx] = h;
                    else             kpz[row * 3072 + 2048 + (cidx - 1024)] = h;
                } else {
                    float v = alpha * acc[mf][nf][r] + addc + bv;
                    const long off = row * (long)ldc + cidx;
                    if (EP == 1) {
                        Cbp[off] = __float2bfloat16(v);
                    } else {
                        if (accumulate) v += Cp[off];
                        Cp[off] = v;
                    }
                }
            }
        }
    }
}

// ---------------------------------------------------------------------------
// Block reductions (256 threads = 4 waves of 64)
// ---------------------------------------------------------------------------
__device__ inline float blockReduceSum(float v, float* red)
{
#pragma unroll
    for (int off = 32; off > 0; off >>= 1) v += __shfl_xor(v, off, 64);
    __syncthreads();
    if ((threadIdx.x & 63) == 0) red[threadIdx.x >> 6] = v;
    __syncthreads();
    return red[0] + red[1] + red[2] + red[3];
}

__device__ inline float blockReduceMax(float v, float* red)
{
#pragma unroll
    for (int off = 32; off > 0; off >>= 1) v = fmaxf(v, __shfl_xor(v, off, 64));
    __syncthreads();
    if ((threadIdx.x & 63) == 0) red[threadIdx.x >> 6] = v;
    __syncthreads();
    return fmaxf(fmaxf(red[0], red[1]), fmaxf(red[2], red[3]));
}

__device__ inline void split_bf16(float v, bf& hi, bf& lo)
{
    hi = __float2bfloat16(v);
    lo = __float2bfloat16(v - __bfloat162float(hi));
}

__device__ __forceinline__ unsigned short bf_bits(float v)
{
    bf h = __float2bfloat16(v);
    return *reinterpret_cast<unsigned short*>(&h);
}

// ---------------------------------------------------------------------------
// Weight prep (once per launch) - all vectorized x4 (G13)
// ---------------------------------------------------------------------------
// Wqkv (2048x1024 fp32) -> Wq2 (2048x2048: [Whi|Wlo]). The qkv GEMM's segB
// table {0,0,1} re-reads Whi for the xlo segment.
__global__ __launch_bounds__(256) void prep_wqkv_kernel(
    const float* __restrict__ W, bf* __restrict__ wq2)
{
    const long i4 = ((long)blockIdx.x * 256 + threadIdx.x) * 4;  // 2048*1024
    const long r = i4 >> 10; const int c = (int)(i4 & 1023);
    const f32x4 s = *(const f32x4*)&W[i4];
    u16x4 h4, l4;
#pragma unroll
    for (int j = 0; j < 4; ++j) {
        bf hi, lo; split_bf16(s[j], hi, lo);
        h4[j] = *reinterpret_cast<unsigned short*>(&hi);
        l4[j] = *reinterpret_cast<unsigned short*>(&lo);
    }
    *(u16x4*)&wq2[r * 2048 + c] = h4;
    *(u16x4*)&wq2[r * 2048 + 1024 + c] = l4;
}

// plain fp32 -> bf16 with source stride (cols % 4 == 0)
__global__ __launch_bounds__(256) void conv_kernel(
    const float* __restrict__ src, bf* __restrict__ dst, int cols, int src_ld, long n)
{
    const long i4 = ((long)blockIdx.x * 256 + threadIdx.x) * 4;
    if (i4 >= n) return;
    const long r = i4 / cols; const int c = (int)(i4 % cols);
    const f32x4 s = *(const f32x4*)&src[r * src_ld + c];
    u16x4 d4;
#pragma unroll
    for (int j = 0; j < 4; ++j) d4[j] = bf_bits(s[j]);
    *(u16x4*)&dst[i4] = d4;
}

// ---------------------------------------------------------------------------
// x -> xhl (S x 2048: [hi|lo]) and xT1 (D x S, bf16 hi). grid (16,16,G),
// 64x64 tiles, fully vectorized (f32x4 loads, u16x8 16B stores).
// The lo plane is consumed only by the qkv GEMM; step 7 later reuses it
// to hold valb so [hi|valb] is contiguous for the fused output GEMM.
// ---------------------------------------------------------------------------
__global__ __launch_bounds__(256) void conv_x_kernel(
    const float* __restrict__ x, bf* __restrict__ xhl, bf* __restrict__ xT1)
{
    __shared__ float t[64][65];
    const int b = blockIdx.z;
    const int c0 = blockIdx.x * 64, r0 = blockIdx.y * 64;
    const int tx = threadIdx.x & 7, ty = threadIdx.x >> 3;   // 8 x 32
    const float* xb = x + (long)b * SS * DD;
    bf* xhlb = xhl + (long)b * SS * 2048;
#pragma unroll
    for (int p = 0; p < 2; ++p) {
        const int r = ty + 32 * p;
        const f32x4 v0 = *(const f32x4*)&xb[(long)(r0 + r) * DD + c0 + tx * 8];
        const f32x4 v1 = *(const f32x4*)&xb[(long)(r0 + r) * DD + c0 + tx * 8 + 4];
        u16x8 hv, lv;
#pragma unroll
        for (int j = 0; j < 4; ++j) {
            bf hi, lo;
            split_bf16(v0[j], hi, lo);
            hv[j] = *reinterpret_cast<unsigned short*>(&hi);
            lv[j] = *reinterpret_cast<unsigned short*>(&lo);
            t[r][tx * 8 + j] = v0[j];
            split_bf16(v1[j], hi, lo);
            hv[j + 4] = *reinterpret_cast<unsigned short*>(&hi);
            lv[j + 4] = *reinterpret_cast<unsigned short*>(&lo);
            t[r][tx * 8 + 4 + j] = v1[j];
        }
        *(u16x8*)&xhlb[(long)(r0 + r) * 2048 + c0 + tx * 8] = hv;
        *(u16x8*)&xhlb[(long)(r0 + r) * 2048 + 1024 + c0 + tx * 8] = lv;
    }
    __syncthreads();
#pragma unroll
    for (int p = 0; p < 2; ++p) {
        const int dd = ty + 32 * p;
        u16x8 o;
#pragma unroll
        for (int j = 0; j < 8; ++j) o[j] = bf_bits(t[tx * 8 + j][dd]);
        *(u16x8*)&xT1[(long)b * DD * SS + (long)(c0 + dd) * SS + r0 + tx * 8] = o;
    }
}

// ---------------------------------------------------------------------------
// In-place L2-normalize plane 2 (offset 2048, row stride 3072) of Q3 (even
// blocks, scaled by Wf[1]) / K3 (odd blocks). grid = nrows*2, block 256.
// ---------------------------------------------------------------------------
__global__ __launch_bounds__(256) void l2norm_fuse_kernel(
    bf* __restrict__ q3, bf* __restrict__ k3, const float* __restrict__ Wf)
{
    __shared__ float red[4];
    const long row = blockIdx.x >> 1;
    const int half = blockIdx.x & 1;
    bf* p = (half ? k3 : q3) + row * 3072 + 2048;
    const int t = threadIdx.x;

    const u16x4 u = *reinterpret_cast<const u16x4*>(p + 4 * t);
    float v[4];
    float ss = 0.0f;
#pragma unroll
    for (int i = 0; i < 4; ++i) {
        unsigned short us = u[i];
        v[i] = __bfloat162float(*reinterpret_cast<const bf*>(&us));
        ss = fmaf(v[i], v[i], ss);
    }
    ss = blockReduceSum(ss, red);
    const float inv = 1.0f / fmaxf(sqrtf(ss), 1e-12f);
    const float scale = half ? inv : inv * Wf[1];   // fold Wf[1] into ctx_q
    u16x4 o;
#pragma unroll
    for (int i = 0; i < 4; ++i) o[i] = bf_bits(v[i] * scale);
    *reinterpret_cast<u16x4*>(p + 4 * t) = o;
}

// ---------------------------------------------------------------------------
// softmax -> mask -> L1 renorm, row 1024, fp32 in -> bf16 out. grid = nrows.
// Vectorized: f32x4 + i32x4 loads, u16x4 store.
// ---------------------------------------------------------------------------
__global__ __launch_bounds__(256) void softmax_mask_kernel(
    const float* __restrict__ attn, const int* __restrict__ mask, bf* __restrict__ attn_bf)
{
    __shared__ float red[4];
    const long row = blockIdx.x;
    const int t4 = threadIdx.x * 4;
    const f32x4 v = *(const f32x4*)(attn + row * SS + t4);
    const i32x4 mv = *(const i32x4*)(mask + row * SS + t4);
    bf* o = attn_bf + row * SS;

    float mx = fmaxf(fmaxf(v[0], v[1]), fmaxf(v[2], v[3]));
    mx = blockReduceMax(mx, red);

    float e[4];
    float s = 0.0f;
#pragma unroll
    for (int i = 0; i < 4; ++i) { e[i] = expf(v[i] - mx); s += e[i]; }
    s = blockReduceSum(s, red);

    float l1 = 0.0f;
#pragma unroll
    for (int i = 0; i < 4; ++i) { e[i] = mv[i] ? e[i] / s : 0.0f; l1 += e[i]; }
    l1 = blockReduceSum(l1, red);
    const float inv = 1.0f / fmaxf(l1, 1e-12f);
    u16x4 ov;
#pragma unroll
    for (int i = 0; i < 4; ++i) ov[i] = bf_bits(e[i] * inv);
    *(u16x4*)(o + t4) = ov;
}

// ---------------------------------------------------------------------------
extern "C" void kernel_launch(void* const* d_in, const int* in_sizes, int n_in,
                              void* d_out, int out_size, void* d_ws, size_t ws_size,
                              hipStream_t stream)
{
    const float* x    = (const float*)d_in[0];
    const int*   mask = (const int*)d_in[1];
    const float* Wqkv = (const float*)d_in[2];
    const float* bqkv = (const float*)d_in[3];
    const float* Wctx = (const float*)d_in[4];
    const float* bctx = (const float*)d_in[5];
    const float* Wf   = (const float*)d_in[6];
    const float* bfp  = (const float*)d_in[7];
    const float* Wo   = (const float*)d_in[8];
    const float* bo   = (const float*)d_in[9];
    float* out = (float*)d_out;

    const long SD = (long)SS * DD;                 // 1M elements per batch

    auto align_up = [](size_t v) { return (v + 255) & ~(size_t)255; };

    // Shared weight buffers
    const size_t sz_wq2  = 2048L * 2048 * 2;       // 8.39 MB [Whi|Wlo]
    const size_t sz_wctx = 2048L * 1024 * 2;       // 4.19 MB
    const size_t sz_wob  = 1024L * 2048 * 2;       // 4.19 MB full Wo
    const size_t SH = align_up(sz_wq2) + align_up(sz_wctx) + align_up(sz_wob);

    // Per-batch pooled regions (total ~23.1 MB):
    //   RX (4.19 MB): xhl [hi|lo]; lo plane becomes valb after step 7
    //   RT (2.10 MB): xT1
    //   RQ (6.29 MB): Q3 [Qhi|Qlo|cq]; attnb aliases head after step 5
    //   RK (6.29 MB): K3 [Khi|Klo|ck]
    //   RY (4.19 MB): adjb bf16 (dead after step 3) -> attn fp32
    const size_t szXL = 1024L * 2048 * 2;
    const size_t szXT = 1024L * 1024 * 2;
    const size_t szQ3 = 1024L * 3072 * 2;
    const size_t szY  = 1024L * 1024 * 4;          // attn fp32 (>= adjb bf16)
    const size_t PB = align_up(szXL) + align_up(szXT) + 2 * align_up(szQ3) +
                      align_up(szY);

    int G = 16;
    while (G > 1 && SH + (size_t)G * PB > ws_size) G >>= 1;

    char* p = (char*)d_ws;
    auto take = [&](size_t bytes) { char* r = p; p += align_up(bytes); return r; };
    bf* Wq2   = (bf*)take(sz_wq2);
    bf* Wctx1 = (bf*)take(sz_wctx);
    bf* Wob   = (bf*)take(sz_wob);
    char* RX = take((size_t)G * szXL);
    char* RT = take((size_t)G * szXT);
    char* RQ = take((size_t)G * szQ3);
    char* RK = take((size_t)G * szQ3);
    char* RY = take((size_t)G * szY);

    bf*    xhl   = (bf*)RX;                        // G x (1024 x 2048)
    bf*    xT1   = (bf*)RT;                        // G x (1024 x 1024)
    bf*    Q3    = (bf*)RQ;                        // G x (1024 x 3072)
    bf*    K3    = (bf*)RK;                        // G x (1024 x 3072)
    bf*    adjb  = (bf*)RY;                        // G x (1024 x 1024) bf16
    float* attn  = (float*)RY;                     // G x (1024 x 1024) fp32
    bf*    attnb = (bf*)RQ;                        // G x (1024 x 1024)

    const dim3 blk(256);
    const dim3 blk5(512);
    const long sXL = 1024L * 2048;
    const long sAT = 1024L * 1024;
    const long sQ3 = 1024L * 3072;

    // Segment tables (byte s = source col offset / 1024 for k in segment s)
    const int segQKV_A = 0x0100;      // [xhi|xlo|(xhi)]
    const int segQKV_B = 0x010000;    // [Whi|(Whi)|Wlo]
    const int segATT_A = 0x02010000;  // [Qhi|(Qhi)|Qlo|cq]
    const int segATT_B = 0x02000100;  // [Khi|Klo|(Khi)|ck]
    const int segOUT   = 0x0100;      // plain 2048-wide

    // --- weight prep (once) ---
    prep_wqkv_kernel<<<dim3((2048L * 1024) / 1024), blk, 0, stream>>>(Wqkv, Wq2);
    conv_kernel<<<dim3((2048L * 1024) / 1024), blk, 0, stream>>>(Wctx, Wctx1, 1024, 1024, 2048L * 1024);
    conv_kernel<<<dim3((1024L * 2048) / 1024), blk, 0, stream>>>(Wo, Wob, 2048, 2048, 1024L * 2048);

    for (int bc0 = 0; bc0 < BB; bc0 += G) {
        const float* xb = x + (long)bc0 * SD;
        const int M = G * 1024;                    // flattened rows this chunk

        // 0. x -> xhl ([hi|lo]), xT1
        conv_x_kernel<<<dim3(16, 16, G), blk, 0, stream>>>(xb, xhl, xT1);

        // 1. qkv = xhi*Whi + xlo*Whi + xhi*Wlo + bqkv  (K=3072 via segment
        //    tables, flat M). Epilogue: Q planes (x Wf0) -> Q3, K -> K3.
        gemm256<2><<<dim3(2048 / 256, M / 256), blk5, 0, stream>>>(
            xhl, 0, 2048, segQKV_A, Wq2, 0, 2048, segQKV_B,
            nullptr, nullptr, Q3, K3, 0, 0, 3072,
            bqkv, Wf, 0, nullptr, 0);

        // 2. adj = bf16(xhi * xhi^T)   (A = B = xhl, per batch)
        gemm256<1><<<dim3(1024 / 256, 1024 / 256, G), blk5, 0, stream>>>(
            xhl, sXL, 2048, 0, xhl, sXL, 2048, 0,
            nullptr, adjb, nullptr, nullptr, sAT, 1024, 1024,
            nullptr, nullptr, 0, nullptr, 0);

        // 3. ctx = adj * Wctx^T + bctx -> bf16 straight into Q3/K3 plane 2
        gemm256<3><<<dim3(2048 / 256, 1024 / 256, G), blk5, 0, stream>>>(
            adjb, sAT, 1024, 0, Wctx1, 0, 1024, 0,
            nullptr, nullptr, Q3, K3, sQ3, 0, 1024,
            bctx, nullptr, 0, nullptr, 0);

        // 4. L2-normalize plane 2 in place (q half scaled by Wf1)
        l2norm_fuse_kernel<<<dim3(G * 1024 * 2), blk, 0, stream>>>(Q3, K3, Wf);

        // 5. attn = Q3 * K3^T + bf   (K=4096 via segment tables:
        //    Wf0*(qhi*khi+qhi*klo+qlo*khi) + Wf1*(cq*ck), single fp32 write)
        gemm256<0><<<dim3(1024 / 256, 1024 / 256, G), blk5, 0, stream>>>(
            Q3, sQ3, 3072, segATT_A, K3, sQ3, 3072, segATT_B,
            attn, nullptr, nullptr, nullptr, sAT, 1024, 4096,
            nullptr, nullptr, 0, bfp, 0);

        // 6. softmax -> mask -> L1 renorm -> attnb
        softmax_mask_kernel<<<dim3(G * 1024), blk, 0, stream>>>(
            attn, mask + (long)bc0 * SS * SS, attnb);

        // 7. valb = attnb * x^T (NT via xT1), bf16 into xhl lo plane
        gemm256<1><<<dim3(1024 / 256, 1024 / 256, G), blk5, 0, stream>>>(
            attnb, sAT, 1024, 0, xT1, sAT, 1024, 0,
            nullptr, xhl + 1024, nullptr, nullptr, sXL, 2048, 1024,
            nullptr, nullptr, 0, nullptr, 0);

        // 8. out = [xhi|valb] * Wo^T + bo   (K=2048, flat M, single write)
        gemm256<0><<<dim3(1024 / 256, M / 256), blk5, 0, stream>>>(
            xhl, 0, 2048, segOUT, Wob, 0, 2048, segOUT,
            out + (long)bc0 * SD, nullptr, nullptr, nullptr, 0, 1024, 2048,
            bo, nullptr, 0, nullptr, 0);
    }
}